// Round 9
// baseline (470.437 us; speedup 1.0000x reference)
//
#include <hip/hip_runtime.h>

#define BATCH 4
#define CH 512
#define NSP 4096   // 64*64 spatial

typedef __attribute__((ext_vector_type(8))) short bfrag8;  // 8 bf16 (4 VGPRs)
typedef __attribute__((ext_vector_type(4))) float f32x4;
typedef unsigned short u16;

#define AS1 __attribute__((address_space(1)))
#define AS3 __attribute__((address_space(3)))
__device__ __forceinline__ void gload16(const void* g, void* l) {
    __builtin_amdgcn_global_load_lds((const AS1 void*)g, (AS3 void*)l, 16, 0, 0);
}

__device__ __forceinline__ void split_bf16(float y, u16& h, u16& l) {
    unsigned int u = __float_as_uint(y);
    h = (u16)(u >> 16);
    float r = y - __uint_as_float(((unsigned int)h) << 16);
    l = (u16)(__float_as_uint(r) >> 16);
}
__device__ __forceinline__ float join_bf16(u16 h, u16 l) {
    return __uint_as_float(((unsigned int)h) << 16) + __uint_as_float(((unsigned int)l) << 16);
}

// ---------------------------------------------------------------------------
// prep 1: x [C][N] view -> XHi/XLo (same layout) + XT1 [n][c] (transpose)
// ---------------------------------------------------------------------------
__global__ __launch_bounds__(256) void k_prep_cn(const float* __restrict__ X,
                                                 u16* __restrict__ XHi,
                                                 u16* __restrict__ XLo,
                                                 u16* __restrict__ XT1hi,
                                                 u16* __restrict__ XT1lo) {
    __shared__ unsigned int t[64][65];
    const size_t boff = (size_t)blockIdx.z * CH * NSP;
    const int c0 = blockIdx.y * 64, n0 = blockIdx.x * 64;
    const int r = threadIdx.x >> 4, col4 = (threadIdx.x & 15) * 4;
#pragma unroll
    for (int it = 0; it < 4; it++) {
        int rl = r + it * 16;
        float4 v = *(const float4*)(X + boff + (size_t)(c0 + rl) * NSP + n0 + col4);
        ushort4 h, l;
        split_bf16(v.x, h.x, l.x);
        split_bf16(v.y, h.y, l.y);
        split_bf16(v.z, h.z, l.z);
        split_bf16(v.w, h.w, l.w);
        *(ushort4*)(XHi + boff + (size_t)(c0 + rl) * NSP + n0 + col4) = h;
        *(ushort4*)(XLo + boff + (size_t)(c0 + rl) * NSP + n0 + col4) = l;
        t[rl][col4 + 0] = ((unsigned int)h.x << 16) | l.x;
        t[rl][col4 + 1] = ((unsigned int)h.y << 16) | l.y;
        t[rl][col4 + 2] = ((unsigned int)h.z << 16) | l.z;
        t[rl][col4 + 3] = ((unsigned int)h.w << 16) | l.w;
    }
    __syncthreads();
#pragma unroll
    for (int it = 0; it < 4; it++) {
        int cl = r + it * 16;
        unsigned int p0 = t[col4 + 0][cl];
        unsigned int p1 = t[col4 + 1][cl];
        unsigned int p2 = t[col4 + 2][cl];
        unsigned int p3 = t[col4 + 3][cl];
        ushort4 hv, lv;
        hv.x = p0 >> 16; hv.y = p1 >> 16; hv.z = p2 >> 16; hv.w = p3 >> 16;
        lv.x = p0 & 0xffff; lv.y = p1 & 0xffff; lv.z = p2 & 0xffff; lv.w = p3 & 0xffff;
        *(ushort4*)(XT1hi + boff + (size_t)(n0 + cl) * CH + c0 + col4) = hv;
        *(ushort4*)(XT1lo + boff + (size_t)(n0 + cl) * CH + c0 + col4) = lv;
    }
}

// prep 2: x [N][C] view -> XT2 [d][n] (transpose)
__global__ __launch_bounds__(256) void k_prep_nc(const float* __restrict__ X,
                                                 u16* __restrict__ XT2hi,
                                                 u16* __restrict__ XT2lo) {
    __shared__ unsigned int t[64][65];
    const size_t boff = (size_t)blockIdx.z * CH * NSP;
    const int n0 = blockIdx.x * 64, d0 = blockIdx.y * 64;
    const int r = threadIdx.x >> 4, col4 = (threadIdx.x & 15) * 4;
#pragma unroll
    for (int it = 0; it < 4; it++) {
        int rl = r + it * 16;
        float4 v = *(const float4*)(X + boff + (size_t)(n0 + rl) * CH + d0 + col4);
        ushort4 h, l;
        split_bf16(v.x, h.x, l.x);
        split_bf16(v.y, h.y, l.y);
        split_bf16(v.z, h.z, l.z);
        split_bf16(v.w, h.w, l.w);
        t[rl][col4 + 0] = ((unsigned int)h.x << 16) | l.x;
        t[rl][col4 + 1] = ((unsigned int)h.y << 16) | l.y;
        t[rl][col4 + 2] = ((unsigned int)h.z << 16) | l.z;
        t[rl][col4 + 3] = ((unsigned int)h.w << 16) | l.w;
    }
    __syncthreads();
#pragma unroll
    for (int it = 0; it < 4; it++) {
        int cl = r + it * 16;
        unsigned int p0 = t[col4 + 0][cl];
        unsigned int p1 = t[col4 + 1][cl];
        unsigned int p2 = t[col4 + 2][cl];
        unsigned int p3 = t[col4 + 3][cl];
        ushort4 hv, lv;
        hv.x = p0 >> 16; hv.y = p1 >> 16; hv.z = p2 >> 16; hv.w = p3 >> 16;
        lv.x = p0 & 0xffff; lv.y = p1 & 0xffff; lv.z = p2 & 0xffff; lv.w = p3 & 0xffff;
        *(ushort4*)(XT2hi + boff + (size_t)(d0 + cl) * NSP + n0 + col4) = hv;
        *(ushort4*)(XT2lo + boff + (size_t)(d0 + cl) * NSP + n0 + col4) = lv;
    }
}

// ---------------------------------------------------------------------------
// k1 MFMA split-K=8 with XCD swizzle; partials -> Pk (aliases Y region)
// ---------------------------------------------------------------------------
__global__ __launch_bounds__(256, 2) void k1_mfma(const u16* __restrict__ XHi,
                                                  const u16* __restrict__ XLo,
                                                  const u16* __restrict__ XT2hi,
                                                  const u16* __restrict__ XT2lo,
                                                  float* __restrict__ Pk) {
    __shared__ __align__(16) char smem[32768];
    char* Ahi = smem;
    char* Alo = smem + 8192;
    char* Bhi = smem + 16384;
    char* Blo = smem + 24576;
    const int bid = blockIdx.x;
    const int xcd = bid & 7;
    const int i1 = bid >> 3;
    const int group = xcd * 4 + (i1 >> 4);
    const int b = group >> 3, kz = group & 7;
    const int tile = i1 & 15;
    const int c0 = (tile >> 2) * 128, d0 = (tile & 3) * 128;
    const size_t boff = (size_t)b * CH * NSP;
    const int tid = threadIdx.x, lane = tid & 63, w = tid >> 6;
    const int wr = w >> 1, wc = w & 1;
    const int rl = lane >> 2;
    const int cb = (lane & 3) * 8;
    f32x4 acc[4][4];
#pragma unroll
    for (int i = 0; i < 4; i++)
#pragma unroll
        for (int j = 0; j < 4; j++) acc[i][j] = (f32x4){0.f, 0.f, 0.f, 0.f};

    const int kbeg = kz * 512, kend = kbeg + 512;
    for (int k0 = kbeg; k0 < kend; k0 += 32) {
#pragma unroll
        for (int s = 0; s < 2; s++) {
            int idx = w * 2 + s;
            int row = 16 * idx + rl;
            gload16(XHi + boff + (size_t)(c0 + row) * NSP + k0 + cb, Ahi + idx * 1024);
            gload16(XLo + boff + (size_t)(c0 + row) * NSP + k0 + cb, Alo + idx * 1024);
            gload16(XT2hi + boff + (size_t)(d0 + row) * NSP + k0 + cb, Bhi + idx * 1024);
            gload16(XT2lo + boff + (size_t)(d0 + row) * NSP + k0 + cb, Blo + idx * 1024);
        }
        __syncthreads();
        bfrag8 ah[4], al[4], bh[4], bl[4];
        const int q16 = (lane >> 4) * 16;
        const int l15 = (lane & 15);
#pragma unroll
        for (int i = 0; i < 4; i++) {
            int offa = (wr * 64 + i * 16 + l15) * 64 + q16;
            ah[i] = *(const bfrag8*)(Ahi + offa);
            al[i] = *(const bfrag8*)(Alo + offa);
            int offb = (wc * 64 + i * 16 + l15) * 64 + q16;
            bh[i] = *(const bfrag8*)(Bhi + offb);
            bl[i] = *(const bfrag8*)(Blo + offb);
        }
#pragma unroll
        for (int i = 0; i < 4; i++)
#pragma unroll
            for (int j = 0; j < 4; j++) {
                acc[i][j] = __builtin_amdgcn_mfma_f32_16x16x32_bf16(ah[i], bh[j], acc[i][j], 0, 0, 0);
                acc[i][j] = __builtin_amdgcn_mfma_f32_16x16x32_bf16(ah[i], bl[j], acc[i][j], 0, 0, 0);
                acc[i][j] = __builtin_amdgcn_mfma_f32_16x16x32_bf16(al[i], bh[j], acc[i][j], 0, 0, 0);
            }
        __syncthreads();
    }
    float* Lb = Pk + (size_t)kz * BATCH * CH * CH + (size_t)b * CH * CH;
    const int col = lane & 15, qr = (lane >> 4) * 4;
#pragma unroll
    for (int i = 0; i < 4; i++)
#pragma unroll
        for (int j = 0; j < 4; j++)
#pragma unroll
            for (int r = 0; r < 4; r++)
                Lb[(size_t)(c0 + wr * 64 + 16 * i + qr + r) * CH + d0 + wc * 64 + 16 * j + col] =
                    acc[i][j][r];
}

__global__ __launch_bounds__(256) void k_combine8(const float* __restrict__ Pk,
                                                  float* __restrict__ Lg) {
    const size_t MM = (size_t)BATCH * CH * CH;
    size_t i = ((size_t)blockIdx.x * 256 + threadIdx.x) * 4;
    float4 s = *(const float4*)(Pk + i);
#pragma unroll
    for (int z = 1; z < 8; z++) {
        float4 v = *(const float4*)(Pk + z * MM + i);
        s.x += v.x; s.y += v.y; s.z += v.z; s.w += v.w;
    }
    *(float4*)(Lg + i) = s;
}

// softmax rows of 512 -> packed hi/lo bf16 in place
__global__ __launch_bounds__(256) void k_softmax_pack512(float* __restrict__ Lg) {
    __shared__ float buf[512];
    __shared__ float red[256];
    const int tid = threadIdx.x;
    float* row = Lg + (size_t)blockIdx.x * 512;
    float2 v = *(const float2*)(row + tid * 2);
    buf[tid * 2] = v.x;
    buf[tid * 2 + 1] = v.y;
    red[tid] = fmaxf(v.x, v.y);
    __syncthreads();
    for (int s = 128; s > 0; s >>= 1) {
        if (tid < s) red[tid] = fmaxf(red[tid], red[tid + s]);
        __syncthreads();
    }
    float m = red[0];
    __syncthreads();
    float e0 = __expf(buf[tid * 2] - m), e1 = __expf(buf[tid * 2 + 1] - m);
    buf[tid * 2] = e0;
    buf[tid * 2 + 1] = e1;
    red[tid] = e0 + e1;
    __syncthreads();
    for (int s = 128; s > 0; s >>= 1) {
        if (tid < s) red[tid] += red[tid + s];
        __syncthreads();
    }
    float inv = 1.0f / red[0];
    u16* u = (u16*)row;
    u16 h0, l0, h1, l1;
    split_bf16(buf[tid * 2] * inv, h0, l0);
    split_bf16(buf[tid * 2 + 1] * inv, h1, l1);
    __syncthreads();
    u[tid * 2] = h0;
    u[tid * 2 + 1] = h1;
    u[512 + tid * 2] = l0;
    u[512 + tid * 2 + 1] = l1;
}

// ---------------------------------------------------------------------------
// k3 MFMA (3-term): Y = A*pq + x. Epilogue writes Yhi/Ylo AND the transposed
// YT [n][c] via per-wave padded-LDS tiles — fused, no separate transpose.
// ---------------------------------------------------------------------------
__global__ __launch_bounds__(256, 2) void k3_mfma(const u16* __restrict__ Lu,
                                                  const u16* __restrict__ XT1hi,
                                                  const u16* __restrict__ XT1lo,
                                                  const float* __restrict__ X,
                                                  u16* __restrict__ Yhi,
                                                  u16* __restrict__ Ylo,
                                                  u16* __restrict__ YThi,
                                                  u16* __restrict__ YTlo) {
    __shared__ __align__(16) char smem[33280];  // 32KB staging; 2x(64x65 u32) transpose
    char* Ahi = smem;
    char* Alo = smem + 8192;
    char* Bhi = smem + 16384;
    char* Blo = smem + 24576;
    const int b = blockIdx.z;
    const u16* Au = Lu + (size_t)b * CH * 1024;
    const size_t boff = (size_t)b * CH * NSP;
    const float* Xb = X + boff;
    const int tid = threadIdx.x, lane = tid & 63, w = tid >> 6;
    const int wr = w >> 1, wc = w & 1;
    const int c0 = blockIdx.y * 128, n0 = blockIdx.x * 128;
    const int rl = lane >> 2;
    const int cb = (lane & 3) * 8;
    f32x4 acc[4][4];
#pragma unroll
    for (int i = 0; i < 4; i++)
#pragma unroll
        for (int j = 0; j < 4; j++) acc[i][j] = (f32x4){0.f, 0.f, 0.f, 0.f};

    for (int k0 = 0; k0 < CH; k0 += 32) {
#pragma unroll
        for (int s = 0; s < 2; s++) {
            int idx = w * 2 + s;
            int row = 16 * idx + rl;
            gload16(Au + (size_t)(c0 + row) * 1024 + k0 + cb, Ahi + idx * 1024);
            gload16(Au + (size_t)(c0 + row) * 1024 + 512 + k0 + cb, Alo + idx * 1024);
            gload16(XT1hi + boff + (size_t)(n0 + row) * CH + k0 + cb, Bhi + idx * 1024);
            gload16(XT1lo + boff + (size_t)(n0 + row) * CH + k0 + cb, Blo + idx * 1024);
        }
        __syncthreads();
        bfrag8 ah[4], al[4], bh[4], bl[4];
        const int q16 = (lane >> 4) * 16;
        const int l15 = (lane & 15);
#pragma unroll
        for (int i = 0; i < 4; i++) {
            int offa = (wr * 64 + i * 16 + l15) * 64 + q16;
            ah[i] = *(const bfrag8*)(Ahi + offa);
            al[i] = *(const bfrag8*)(Alo + offa);
            int offb = (wc * 64 + i * 16 + l15) * 64 + q16;
            bh[i] = *(const bfrag8*)(Bhi + offb);
            bl[i] = *(const bfrag8*)(Blo + offb);
        }
#pragma unroll
        for (int i = 0; i < 4; i++)
#pragma unroll
            for (int j = 0; j < 4; j++) {
                acc[i][j] = __builtin_amdgcn_mfma_f32_16x16x32_bf16(ah[i], bh[j], acc[i][j], 0, 0, 0);
                acc[i][j] = __builtin_amdgcn_mfma_f32_16x16x32_bf16(ah[i], bl[j], acc[i][j], 0, 0, 0);
                acc[i][j] = __builtin_amdgcn_mfma_f32_16x16x32_bf16(al[i], bh[j], acc[i][j], 0, 0, 0);
            }
        __syncthreads();
    }
    u16* Yhb = Yhi + boff;
    u16* Ylb = Ylo + boff;
    u16* YThb = YThi + boff;  // [n][c], same per-batch element count
    u16* YTlb = YTlo + boff;
    const int col = lane & 15, qr = (lane >> 4) * 4;
    unsigned int* Tb = (unsigned int*)smem;  // two 64x65 u32 wave-tiles
#pragma unroll
    for (int round = 0; round < 2; round++) {
        if (wr == round) {
            unsigned int* T = Tb + wc * 4160;
#pragma unroll
            for (int i = 0; i < 4; i++)
#pragma unroll
                for (int j = 0; j < 4; j++)
#pragma unroll
                    for (int r = 0; r < 4; r++) {
                        int cl = 16 * i + qr + r;       // c within wave tile
                        int nl = 16 * j + col;          // n within wave tile
                        int c = c0 + wr * 64 + cl;
                        int n = n0 + wc * 64 + nl;
                        float v = acc[i][j][r] + Xb[(size_t)c * NSP + n];
                        u16 h, l;
                        split_bf16(v, h, l);
                        Yhb[(size_t)c * NSP + n] = h;
                        Ylb[(size_t)c * NSP + n] = l;
                        T[nl * 65 + cl] = ((unsigned int)h << 16) | l;
                    }
        }
        __syncthreads();
        if (wr == round) {
            unsigned int* T = Tb + wc * 4160;
            const int cl = (lane & 15) * 4;
#pragma unroll
            for (int rep = 0; rep < 16; rep++) {
                int nq = rep * 4 + (lane >> 4);
                unsigned int p0 = T[nq * 65 + cl];
                unsigned int p1 = T[nq * 65 + cl + 1];
                unsigned int p2 = T[nq * 65 + cl + 2];
                unsigned int p3 = T[nq * 65 + cl + 3];
                ushort4 hv, lv;
                hv.x = p0 >> 16; hv.y = p1 >> 16; hv.z = p2 >> 16; hv.w = p3 >> 16;
                lv.x = p0 & 0xffff; lv.y = p1 & 0xffff; lv.z = p2 & 0xffff; lv.w = p3 & 0xffff;
                size_t o = (size_t)(n0 + wc * 64 + nq) * CH + c0 + wr * 64 + cl;
                *(ushort4*)(YThb + o) = hv;
                *(ushort4*)(YTlb + o) = lv;
            }
        }
        __syncthreads();
    }
}

// ---------------------------------------------------------------------------
// k4 MFMA symmetric (3-term) — R8: triangular 128x128 grid, R4-style pipelined
// schedule (3-term phases, counted vmcnt, single barrier/phase, setprio,
// both-sides XOR swizzle), now 8 WAVES (512 thr, 2x4 wave grid, wave tile
// 64x32, acc[4][2]). LDS still 64KB -> 2 blocks/CU = 16 waves/CU = 4
// waves/SIMD (was 2) — doubles per-SIMD arbitration depth so one wave's
// reads/waits hide under another's MFMAs. VGPR ~90 (acc 32 + frags 48),
// safely under the 128 cap of __launch_bounds__(512,2) (R6 spill avoided).
//
// STAGE = 1 gload16/thread (unit 8KB = 512thr x 16B), so the ledger counts
// units directly (FIFO, in-order):
//   prologue U0(0),U2(0),U1(0),U3(0),U0(1),U2(1),U1(1) = 7; vmcnt(5)->U0U2(0)
//   P1(t): +U3(t+1), vmcnt(5)->U1(t);  P2(t): +U0(t+2),U2(t+2), vmcnt(6)->U3(t)
//   P3(t): +U1(t+2), vmcnt(5)->U0U2(t+1)   [invariant 5 at loop top]
//   t=14: +U3(15): 5 / 4 / 2;  t=15: 1 / 0 / bare
// WAR windows identical to R7 (same phase/barrier structure).
// ---------------------------------------------------------------------------
__global__ __launch_bounds__(512, 2) void k4_mfma(const u16* __restrict__ YThi0,
                                                  const u16* __restrict__ YTlo0,
                                                  float* __restrict__ S0) {
    __shared__ __align__(16) char smem[65536];
    const int tid = threadIdx.x, lane = tid & 63, w = tid >> 6;
    const int wr = w >> 2, wc = w & 3;  // 2x4 wave grid; wave tile 64(r) x 32(c)
    const int rb = blockIdx.y;
    const u16* Phi = YThi0 + (size_t)rb * NSP * CH;
    const u16* Plo = YTlo0 + (size_t)rb * NSP * CH;
    float* S = S0 + (size_t)rb * NSP * NSP;
    int idx = blockIdx.x;
    int bi = (int)((sqrtf(8.f * (float)idx + 1.f) - 1.f) * 0.5f);
    while ((bi + 1) * (bi + 2) / 2 <= idx) bi++;
    while (bi * (bi + 1) / 2 > idx) bi--;
    int bj = idx - bi * (bi + 1) / 2;
    const int n0 = bi * 128, m0 = bj * 128;
    const bool diag = (bi == bj);

    const int rl = lane >> 2;        // staging row within 16-row chunk
    const int cb = (((lane & 3) ^ ((lane >> 3) & 3)) * 8);     // swizzled src chunk
    const int l15 = lane & 15;
    const int q16 = (((lane >> 4) ^ ((lane >> 1) & 3)) * 16);  // swizzled read slot

    // stage one 128x32 u16 unit (u: 0=Ahi,1=Alo,2=Bhi,3=Blo) into buf (kt&1)
    // 512 threads x 1 gload16 = 8KB; wave w covers rows w*16 .. w*16+15
    auto STAGE = [&](const u16* mat, int r0, int kt, int u) {
        char* dst = smem + (kt & 1) * 32768 + u * 8192 + w * 1024;
        const int k0 = kt * 32;
        gload16(mat + (size_t)(r0 + w * 16 + rl) * CH + k0 + cb, dst);
    };

    f32x4 acc[4][2];
#pragma unroll
    for (int i = 0; i < 4; i++)
#pragma unroll
        for (int j = 0; j < 2; j++) acc[i][j] = (f32x4){0.f, 0.f, 0.f, 0.f};
    bfrag8 ah[4], al[4], bh[2], bl[2];

    auto LDA = [&](const char* base, bfrag8* a) {
#pragma unroll
        for (int i = 0; i < 4; i++)
            a[i] = *(const bfrag8*)(base + (wr * 64 + i * 16 + l15) * 64 + q16);
    };
    auto LDB = [&](const char* base, bfrag8* bv) {
#pragma unroll
        for (int j = 0; j < 2; j++)
            bv[j] = *(const bfrag8*)(base + (wc * 32 + j * 16 + l15) * 64 + q16);
    };
    auto MMA = [&](const bfrag8* a, const bfrag8* bv) {
        __builtin_amdgcn_s_setprio(1);
#pragma unroll
        for (int i = 0; i < 4; i++)
#pragma unroll
            for (int j = 0; j < 2; j++)
                acc[i][j] = __builtin_amdgcn_mfma_f32_16x16x32_bf16(a[i], bv[j], acc[i][j], 0, 0, 0);
        __builtin_amdgcn_s_setprio(0);
    };

#define WAITB(N)                                          \
    asm volatile("s_waitcnt vmcnt(" #N ")" ::: "memory"); \
    __builtin_amdgcn_sched_barrier(0);                    \
    __builtin_amdgcn_s_barrier();

    // prologue
    STAGE(Phi, n0, 0, 0);
    STAGE(Phi, m0, 0, 2);
    STAGE(Plo, n0, 0, 1);
    STAGE(Plo, m0, 0, 3);
    STAGE(Phi, n0, 1, 0);
    STAGE(Phi, m0, 1, 2);
    STAGE(Plo, n0, 1, 1);
    WAITB(5)

    for (int t = 0; t < 14; ++t) {
        const char* buf = smem + (t & 1) * 32768;
        // P1: hh
        LDA(buf, ah);
        LDB(buf + 16384, bh);
        STAGE(Plo, m0, t + 1, 3);
        WAITB(5)
        MMA(ah, bh);
        // P2: lh
        LDA(buf + 8192, al);
        STAGE(Phi, n0, t + 2, 0);
        STAGE(Phi, m0, t + 2, 2);
        WAITB(6)
        MMA(al, bh);
        // P3: hl
        LDB(buf + 24576, bl);
        STAGE(Plo, n0, t + 2, 1);
        WAITB(5)
        MMA(ah, bl);
    }
    {  // t = 14 (buf0): stage only U3(15)
        const char* buf = smem;
        LDA(buf, ah);
        LDB(buf + 16384, bh);
        STAGE(Plo, m0, 15, 3);
        WAITB(5)
        MMA(ah, bh);
        LDA(buf + 8192, al);
        WAITB(4)
        MMA(al, bh);
        LDB(buf + 24576, bl);
        WAITB(2)
        MMA(ah, bl);
    }
    {  // t = 15 (buf1): no staging, drain
        const char* buf = smem + 32768;
        LDA(buf, ah);
        LDB(buf + 16384, bh);
        WAITB(1)
        MMA(ah, bh);
        LDA(buf + 8192, al);
        WAITB(0)
        MMA(al, bh);
        LDB(buf + 24576, bl);
        __builtin_amdgcn_sched_barrier(0);
        __builtin_amdgcn_s_barrier();
        MMA(ah, bl);
    }
#undef WAITB

    const int col = lane & 15, qr = (lane >> 4) * 4;
#pragma unroll
    for (int i = 0; i < 4; i++)
#pragma unroll
        for (int j = 0; j < 2; j++)
#pragma unroll
            for (int r = 0; r < 4; r++)
                S[(size_t)(n0 + wr * 64 + 16 * i + qr + r) * NSP + m0 + wc * 32 + 16 * j + col] =
                    acc[i][j][r];
    if (!diag) {  // mirror tile via per-wave padded LDS transpose (wr rounds)
        float* Tbase = (float*)smem;
#pragma unroll
        for (int round = 0; round < 2; round++) {
            __syncthreads();
            if (wr == round) {
                float* T = Tbase + wc * (32 * 68);
#pragma unroll
                for (int i = 0; i < 4; i++)
#pragma unroll
                    for (int j = 0; j < 2; j++)
#pragma unroll
                        for (int r = 0; r < 4; r++)
                            T[(16 * j + col) * 68 + 16 * i + qr + r] = acc[i][j][r];
            }
            __syncthreads();
            if (wr == round) {
                float* T = Tbase + wc * (32 * 68);
                const int rq = (lane & 15) * 4;
#pragma unroll
                for (int rep = 0; rep < 8; rep++) {
                    int cq = rep * 4 + (lane >> 4);
                    float4 v = *(const float4*)(T + cq * 68 + rq);
                    *(float4*)(S + (size_t)(m0 + wc * 32 + cq) * NSP + n0 + wr * 64 + rq) = v;
                }
            }
        }
    }
}

// softmax rows of 4096 over contiguous S0|S1 (grid 8192); writes hi plane only
__global__ __launch_bounds__(256) void k_softmax_pack(float* __restrict__ S) {
    __shared__ float buf[4096];
    __shared__ float red[256];
    const int tid = threadIdx.x;
    float* row = S + (size_t)blockIdx.x * NSP;
    float m = -INFINITY;
#pragma unroll
    for (int it = 0; it < 4; it++) {
        int i = (tid + it * 256) * 4;
        float4 v = *(const float4*)(row + i);
        buf[i] = v.x; buf[i + 1] = v.y; buf[i + 2] = v.z; buf[i + 3] = v.w;
        m = fmaxf(m, fmaxf(fmaxf(v.x, v.y), fmaxf(v.z, v.w)));
    }
    red[tid] = m;
    __syncthreads();
    for (int s = 128; s > 0; s >>= 1) {
        if (tid < s) red[tid] = fmaxf(red[tid], red[tid + s]);
        __syncthreads();
    }
    m = red[0];
    __syncthreads();
    float sum = 0.f;
#pragma unroll
    for (int it = 0; it < 4; it++) {
        int i = (tid + it * 256) * 4;
        float e0 = __expf(buf[i] - m), e1 = __expf(buf[i + 1] - m);
        float e2 = __expf(buf[i + 2] - m), e3 = __expf(buf[i + 3] - m);
        buf[i] = e0; buf[i + 1] = e1; buf[i + 2] = e2; buf[i + 3] = e3;
        sum += e0 + e1 + e2 + e3;
    }
    red[tid] = sum;
    __syncthreads();
    for (int s = 128; s > 0; s >>= 1) {
        if (tid < s) red[tid] += red[tid + s];
        __syncthreads();
    }
    float inv = 1.0f / red[0];
    u16* u = (u16*)row;
#pragma unroll
    for (int it = 0; it < 4; it++) {
        int i = (tid + it * 256) * 4;
        ushort4 hv;
        hv.x = (u16)(__float_as_uint(buf[i] * inv) >> 16);
        hv.y = (u16)(__float_as_uint(buf[i + 1] * inv) >> 16);
        hv.z = (u16)(__float_as_uint(buf[i + 2] * inv) >> 16);
        hv.w = (u16)(__float_as_uint(buf[i + 3] * inv) >> 16);
        *(ushort4*)(u + i) = hv;
    }
}

// ---------------------------------------------------------------------------
// k6 MFMA 1-term, split-K=2, 2 batches/launch — pipelined, single barrier
// per phase (unchanged; passing).
// ---------------------------------------------------------------------------
__global__ __launch_bounds__(512, 2) void k6_mfma(const u16* __restrict__ Yhi0,
                                                  const u16* __restrict__ Ylo0,
                                                  const u16* __restrict__ Su,
                                                  float* __restrict__ Out0,
                                                  float* __restrict__ Pp0,
                                                  float* __restrict__ Pp1) {
    __shared__ __align__(16) char smem[73728];  // 3 x (8KB A + 16KB B)
    const int tid = threadIdx.x, lane = tid & 63, w = tid >> 6;
    const int wr = w >> 2, wc = w & 3;  // 2(c) x 4(m); wave tile 64x64
    const int m0 = blockIdx.x * 256, c0 = blockIdx.y * 128;
    const int rb = blockIdx.z >> 1, kz = blockIdx.z & 1;
    const u16* Yhi = Yhi0 + (size_t)rb * CH * NSP;
    const u16* Ylo = Ylo0 + (size_t)rb * CH * NSP;
    const u16* Pu = Su + (size_t)rb * NSP * NSP * 2;  // S batch stride in u16 units
    float* Out = Out0 + (size_t)rb * CH * NSP;
    float* Ppart = rb ? Pp1 : Pp0;
    const int kb = kz * 2048;
    const int rl = lane >> 2;
    const int cb = (((lane & 3) ^ ((lane >> 3) & 3)) * 8);     // swizzled src chunk
    const int l15 = lane & 15;
    const int q16 = (((lane >> 4) ^ ((lane >> 1) & 3)) * 16);  // swizzled read slot

    // stage K-tile kt into slot: A = Yhi[c0..+128][32], B = Pu[m0..+256][32]
    auto STAGE = [&](int kt, int slot) {
        char* dst = smem + slot * 24576;
        const int k0 = kb + kt * 32;
        gload16(Yhi + (size_t)(c0 + w * 16 + rl) * NSP + k0 + cb, dst + w * 1024);
#pragma unroll
        for (int s = 0; s < 2; s++) {
            int idx = w * 2 + s;
            gload16(Pu + (size_t)(m0 + idx * 16 + rl) * 8192 + k0 + cb,
                    dst + 8192 + idx * 1024);
        }
    };

    f32x4 acc[4][4];
#pragma unroll
    for (int i = 0; i < 4; i++)
#pragma unroll
        for (int j = 0; j < 4; j++) acc[i][j] = (f32x4){0.f, 0.f, 0.f, 0.f};
    bfrag8 ah[4], bh[4];

#define K6PHASE(SLOT, STSLOT, T, DOSTAGE, WN)                                            \
    {                                                                                    \
        const char* bA = smem + (SLOT)*24576;                                            \
        const char* bB = bA + 8192;                                                      \
        _Pragma("unroll") for (int i = 0; i < 4; i++) ah[i] =                            \
            *(const bfrag8*)(bA + (wr * 64 + i * 16 + l15) * 64 + q16);                  \
        _Pragma("unroll") for (int j = 0; j < 4; j++) bh[j] =                            \
            *(const bfrag8*)(bB + (wc * 64 + j * 16 + l15) * 64 + q16);                  \
        if (DOSTAGE) STAGE((T) + 2, (STSLOT));                                           \
        asm volatile("s_waitcnt vmcnt(" #WN ")" ::: "memory");                           \
        __builtin_amdgcn_sched_barrier(0);                                               \
        __builtin_amdgcn_s_barrier();                                                    \
        __builtin_amdgcn_s_setprio(1);                                                   \
        _Pragma("unroll") for (int i = 0; i < 4; i++)                                    \
            _Pragma("unroll") for (int j = 0; j < 4; j++) acc[i][j] =                    \
                __builtin_amdgcn_mfma_f32_16x16x32_bf16(ah[i], bh[j], acc[i][j], 0, 0, 0); \
        __builtin_amdgcn_s_setprio(0);                                                   \
    }

    // prologue: tiles 0,1 in flight; wait tile 0
    STAGE(0, 0);
    STAGE(1, 1);
    asm volatile("s_waitcnt vmcnt(3)" ::: "memory");
    __builtin_amdgcn_sched_barrier(0);
    __builtin_amdgcn_s_barrier();

    for (int tt = 0; tt < 60; tt += 3) {
        K6PHASE(0, 2, tt, true, 3)
        K6PHASE(1, 0, tt + 1, true, 3)
        K6PHASE(2, 1, tt + 2, true, 3)
    }
    K6PHASE(0, 2, 60, true, 3)   // stages 62 -> slot 2
    K6PHASE(1, 0, 61, true, 3)   // stages 63 -> slot 0
    K6PHASE(2, 0, 62, false, 0)  // drain: tile 63 landed
    K6PHASE(0, 0, 63, false, 0)
#undef K6PHASE

    const int col = lane & 15, qr = (lane >> 4) * 4;
    if (kz == 0) {
#pragma unroll
        for (int i = 0; i < 4; i++)
#pragma unroll
            for (int j = 0; j < 4; j++)
#pragma unroll
                for (int r = 0; r < 4; r++) {
                    int c = c0 + wr * 64 + 16 * i + qr + r;
                    int mm = m0 + wc * 64 + 16 * j + col;
                    Out[(size_t)c * NSP + mm] =
                        acc[i][j][r] +
                        join_bf16(Yhi[(size_t)c * NSP + mm], Ylo[(size_t)c * NSP + mm]);
                }
    } else {
#pragma unroll
        for (int i = 0; i < 4; i++)
#pragma unroll
            for (int j = 0; j < 4; j++)
#pragma unroll
                for (int r = 0; r < 4; r++) {
                    int c = c0 + wr * 64 + 16 * i + qr + r;
                    int mm = m0 + wc * 64 + 16 * j + col;
                    Ppart[(size_t)c * NSP + mm] = acc[i][j][r];
                }
    }
}

// out[b] += Ppart[b] for the round's 2 batches
__global__ __launch_bounds__(256) void k_fixup(float* __restrict__ Out0,
                                               const float* __restrict__ Pp0,
                                               const float* __restrict__ Pp1) {
    const size_t CN = (size_t)CH * NSP;
    const int b = blockIdx.y;
    const float* P = b ? Pp1 : Pp0;
    float* O = Out0 + (size_t)b * CN;
    size_t i = ((size_t)blockIdx.x * 256 + threadIdx.x) * 4;
    float4 o = *(const float4*)(O + i);
    float4 a = *(const float4*)(P + i);
    o.x += a.x; o.y += a.y; o.z += a.z; o.w += a.w;
    *(float4*)(O + i) = o;
}

extern "C" void kernel_launch(void* const* d_in, const int* in_sizes, int n_in,
                              void* d_out, int out_size, void* d_ws, size_t ws_size,
                              hipStream_t stream) {
    const float* x = (const float*)d_in[0];
    float* out = (float*)d_out;

    // workspace layout (196 MB):
    //   [0,128MB): S0|S1 fp32 score buffers; aliased by X-prep [0,96MB) (dead after k3)
    //   [128,192MB): Yhi|Ylo|YThi|YTlo (YT per-batch 4MB slices)
    //       Pk (k1 partials, 32MB) aliases Yhi|Ylo (dead before k3)
    //       k6 round-r partials alias the YT slices of round r's batches (dead after k4)
    //   [192,196MB): Lg
    char* p = (char*)d_ws;
    const size_t SZ16 = (size_t)BATCH * CH * NSP * 2;  // 16 MB
    const size_t HALF = SZ16 / 2;                      // 8 MB = CH*NSP*4
    u16* XHi = (u16*)p;
    u16* XLo = (u16*)(p + SZ16);
    u16* XT2hi = (u16*)(p + 2 * SZ16);
    u16* XT2lo = (u16*)(p + 3 * SZ16);
    u16* XT1hi = (u16*)(p + 4 * SZ16);
    u16* XT1lo = (u16*)(p + 5 * SZ16);
    float* S = (float*)p;
    u16* Yhi = (u16*)(p + 8 * SZ16);
    u16* Ylo = (u16*)(p + 9 * SZ16);
    u16* YThi = (u16*)(p + 10 * SZ16);
    u16* YTlo = (u16*)(p + 11 * SZ16);
    float* Pk = (float*)(p + 8 * SZ16);
    float* Lg = (float*)(p + 12 * SZ16);

    // Stage 1: channel attention
    k_prep_cn<<<dim3(NSP / 64, CH / 64, BATCH), 256, 0, stream>>>(x, XHi, XLo, XT1hi, XT1lo);
    k_prep_nc<<<dim3(NSP / 64, CH / 64, BATCH), 256, 0, stream>>>(x, XT2hi, XT2lo);
    k1_mfma<<<dim3(512), 256, 0, stream>>>(XHi, XLo, XT2hi, XT2lo, Pk);
    k_combine8<<<dim3((BATCH * CH * CH) / (4 * 256)), 256, 0, stream>>>(Pk, Lg);
    k_softmax_pack512<<<dim3(BATCH * CH), 256, 0, stream>>>(Lg);
    k3_mfma<<<dim3(NSP / 128, CH / 128, BATCH), 256, 0, stream>>>((const u16*)Lg, XT1hi, XT1lo, x,
                                                                  Yhi, Ylo, YThi, YTlo);

    // Stage 2: positional attention, 2 batches per round
    const int TRI = (NSP / 128) * (NSP / 128 + 1) / 2;  // 528
    for (int round = 0; round < 2; round++) {
        const size_t b0 = (size_t)(2 * round);
        float* Pp0 = (float*)((char*)YThi + round * HALF);
        float* Pp1 = (float*)((char*)YTlo + round * HALF);
        k4_mfma<<<dim3(TRI, 2), 512, 0, stream>>>(YThi + b0 * NSP * CH, YTlo + b0 * NSP * CH, S);
        k_softmax_pack<<<dim3(2 * NSP), 256, 0, stream>>>(S);
        k6_mfma<<<dim3(NSP / 256, CH / 128, 4), 512, 0, stream>>>(Yhi + b0 * CH * NSP,
                                                                  Ylo + b0 * CH * NSP,
                                                                  (const u16*)S,
                                                                  out + b0 * CH * NSP, Pp0, Pp1);
        k_fixup<<<dim3((CH * NSP) / (4 * 256), 2), 256, 0, stream>>>(out + b0 * CH * NSP, Pp0, Pp1);
    }
}

// Round 10
// 464.919 us; speedup vs baseline: 1.0119x; 1.0119x over previous
//
#include <hip/hip_runtime.h>

#define BATCH 4
#define CH 512
#define NSP 4096   // 64*64 spatial

typedef __attribute__((ext_vector_type(8))) short bfrag8;  // 8 bf16 (4 VGPRs)
typedef __attribute__((ext_vector_type(4))) float f32x4;
typedef unsigned short u16;

#define AS1 __attribute__((address_space(1)))
#define AS3 __attribute__((address_space(3)))
__device__ __forceinline__ void gload16(const void* g, void* l) {
    __builtin_amdgcn_global_load_lds((const AS1 void*)g, (AS3 void*)l, 16, 0, 0);
}

__device__ __forceinline__ void split_bf16(float y, u16& h, u16& l) {
    unsigned int u = __float_as_uint(y);
    h = (u16)(u >> 16);
    float r = y - __uint_as_float(((unsigned int)h) << 16);
    l = (u16)(__float_as_uint(r) >> 16);
}
__device__ __forceinline__ float join_bf16(u16 h, u16 l) {
    return __uint_as_float(((unsigned int)h) << 16) + __uint_as_float(((unsigned int)l) << 16);
}

// ---------------------------------------------------------------------------
// prep 1: x [C][N] view -> XHi/XLo (same layout) + XT1 [n][c] (transpose)
// ---------------------------------------------------------------------------
__global__ __launch_bounds__(256) void k_prep_cn(const float* __restrict__ X,
                                                 u16* __restrict__ XHi,
                                                 u16* __restrict__ XLo,
                                                 u16* __restrict__ XT1hi,
                                                 u16* __restrict__ XT1lo) {
    __shared__ unsigned int t[64][65];
    const size_t boff = (size_t)blockIdx.z * CH * NSP;
    const int c0 = blockIdx.y * 64, n0 = blockIdx.x * 64;
    const int r = threadIdx.x >> 4, col4 = (threadIdx.x & 15) * 4;
#pragma unroll
    for (int it = 0; it < 4; it++) {
        int rl = r + it * 16;
        float4 v = *(const float4*)(X + boff + (size_t)(c0 + rl) * NSP + n0 + col4);
        ushort4 h, l;
        split_bf16(v.x, h.x, l.x);
        split_bf16(v.y, h.y, l.y);
        split_bf16(v.z, h.z, l.z);
        split_bf16(v.w, h.w, l.w);
        *(ushort4*)(XHi + boff + (size_t)(c0 + rl) * NSP + n0 + col4) = h;
        *(ushort4*)(XLo + boff + (size_t)(c0 + rl) * NSP + n0 + col4) = l;
        t[rl][col4 + 0] = ((unsigned int)h.x << 16) | l.x;
        t[rl][col4 + 1] = ((unsigned int)h.y << 16) | l.y;
        t[rl][col4 + 2] = ((unsigned int)h.z << 16) | l.z;
        t[rl][col4 + 3] = ((unsigned int)h.w << 16) | l.w;
    }
    __syncthreads();
#pragma unroll
    for (int it = 0; it < 4; it++) {
        int cl = r + it * 16;
        unsigned int p0 = t[col4 + 0][cl];
        unsigned int p1 = t[col4 + 1][cl];
        unsigned int p2 = t[col4 + 2][cl];
        unsigned int p3 = t[col4 + 3][cl];
        ushort4 hv, lv;
        hv.x = p0 >> 16; hv.y = p1 >> 16; hv.z = p2 >> 16; hv.w = p3 >> 16;
        lv.x = p0 & 0xffff; lv.y = p1 & 0xffff; lv.z = p2 & 0xffff; lv.w = p3 & 0xffff;
        *(ushort4*)(XT1hi + boff + (size_t)(n0 + cl) * CH + c0 + col4) = hv;
        *(ushort4*)(XT1lo + boff + (size_t)(n0 + cl) * CH + c0 + col4) = lv;
    }
}

// prep 2: x [N][C] view -> XT2 [d][n] (transpose)
__global__ __launch_bounds__(256) void k_prep_nc(const float* __restrict__ X,
                                                 u16* __restrict__ XT2hi,
                                                 u16* __restrict__ XT2lo) {
    __shared__ unsigned int t[64][65];
    const size_t boff = (size_t)blockIdx.z * CH * NSP;
    const int n0 = blockIdx.x * 64, d0 = blockIdx.y * 64;
    const int r = threadIdx.x >> 4, col4 = (threadIdx.x & 15) * 4;
#pragma unroll
    for (int it = 0; it < 4; it++) {
        int rl = r + it * 16;
        float4 v = *(const float4*)(X + boff + (size_t)(n0 + rl) * CH + d0 + col4);
        ushort4 h, l;
        split_bf16(v.x, h.x, l.x);
        split_bf16(v.y, h.y, l.y);
        split_bf16(v.z, h.z, l.z);
        split_bf16(v.w, h.w, l.w);
        t[rl][col4 + 0] = ((unsigned int)h.x << 16) | l.x;
        t[rl][col4 + 1] = ((unsigned int)h.y << 16) | l.y;
        t[rl][col4 + 2] = ((unsigned int)h.z << 16) | l.z;
        t[rl][col4 + 3] = ((unsigned int)h.w << 16) | l.w;
    }
    __syncthreads();
#pragma unroll
    for (int it = 0; it < 4; it++) {
        int cl = r + it * 16;
        unsigned int p0 = t[col4 + 0][cl];
        unsigned int p1 = t[col4 + 1][cl];
        unsigned int p2 = t[col4 + 2][cl];
        unsigned int p3 = t[col4 + 3][cl];
        ushort4 hv, lv;
        hv.x = p0 >> 16; hv.y = p1 >> 16; hv.z = p2 >> 16; hv.w = p3 >> 16;
        lv.x = p0 & 0xffff; lv.y = p1 & 0xffff; lv.z = p2 & 0xffff; lv.w = p3 & 0xffff;
        *(ushort4*)(XT2hi + boff + (size_t)(d0 + cl) * NSP + n0 + col4) = hv;
        *(ushort4*)(XT2lo + boff + (size_t)(d0 + cl) * NSP + n0 + col4) = lv;
    }
}

// ---------------------------------------------------------------------------
// k1 MFMA split-K=8 with XCD swizzle; partials -> Pk (aliases Y region)
// ---------------------------------------------------------------------------
__global__ __launch_bounds__(256, 2) void k1_mfma(const u16* __restrict__ XHi,
                                                  const u16* __restrict__ XLo,
                                                  const u16* __restrict__ XT2hi,
                                                  const u16* __restrict__ XT2lo,
                                                  float* __restrict__ Pk) {
    __shared__ __align__(16) char smem[32768];
    char* Ahi = smem;
    char* Alo = smem + 8192;
    char* Bhi = smem + 16384;
    char* Blo = smem + 24576;
    const int bid = blockIdx.x;
    const int xcd = bid & 7;
    const int i1 = bid >> 3;
    const int group = xcd * 4 + (i1 >> 4);
    const int b = group >> 3, kz = group & 7;
    const int tile = i1 & 15;
    const int c0 = (tile >> 2) * 128, d0 = (tile & 3) * 128;
    const size_t boff = (size_t)b * CH * NSP;
    const int tid = threadIdx.x, lane = tid & 63, w = tid >> 6;
    const int wr = w >> 1, wc = w & 1;
    const int rl = lane >> 2;
    const int cb = (lane & 3) * 8;
    f32x4 acc[4][4];
#pragma unroll
    for (int i = 0; i < 4; i++)
#pragma unroll
        for (int j = 0; j < 4; j++) acc[i][j] = (f32x4){0.f, 0.f, 0.f, 0.f};

    const int kbeg = kz * 512, kend = kbeg + 512;
    for (int k0 = kbeg; k0 < kend; k0 += 32) {
#pragma unroll
        for (int s = 0; s < 2; s++) {
            int idx = w * 2 + s;
            int row = 16 * idx + rl;
            gload16(XHi + boff + (size_t)(c0 + row) * NSP + k0 + cb, Ahi + idx * 1024);
            gload16(XLo + boff + (size_t)(c0 + row) * NSP + k0 + cb, Alo + idx * 1024);
            gload16(XT2hi + boff + (size_t)(d0 + row) * NSP + k0 + cb, Bhi + idx * 1024);
            gload16(XT2lo + boff + (size_t)(d0 + row) * NSP + k0 + cb, Blo + idx * 1024);
        }
        __syncthreads();
        bfrag8 ah[4], al[4], bh[4], bl[4];
        const int q16 = (lane >> 4) * 16;
        const int l15 = (lane & 15);
#pragma unroll
        for (int i = 0; i < 4; i++) {
            int offa = (wr * 64 + i * 16 + l15) * 64 + q16;
            ah[i] = *(const bfrag8*)(Ahi + offa);
            al[i] = *(const bfrag8*)(Alo + offa);
            int offb = (wc * 64 + i * 16 + l15) * 64 + q16;
            bh[i] = *(const bfrag8*)(Bhi + offb);
            bl[i] = *(const bfrag8*)(Blo + offb);
        }
#pragma unroll
        for (int i = 0; i < 4; i++)
#pragma unroll
            for (int j = 0; j < 4; j++) {
                acc[i][j] = __builtin_amdgcn_mfma_f32_16x16x32_bf16(ah[i], bh[j], acc[i][j], 0, 0, 0);
                acc[i][j] = __builtin_amdgcn_mfma_f32_16x16x32_bf16(ah[i], bl[j], acc[i][j], 0, 0, 0);
                acc[i][j] = __builtin_amdgcn_mfma_f32_16x16x32_bf16(al[i], bh[j], acc[i][j], 0, 0, 0);
            }
        __syncthreads();
    }
    float* Lb = Pk + (size_t)kz * BATCH * CH * CH + (size_t)b * CH * CH;
    const int col = lane & 15, qr = (lane >> 4) * 4;
#pragma unroll
    for (int i = 0; i < 4; i++)
#pragma unroll
        for (int j = 0; j < 4; j++)
#pragma unroll
            for (int r = 0; r < 4; r++)
                Lb[(size_t)(c0 + wr * 64 + 16 * i + qr + r) * CH + d0 + wc * 64 + 16 * j + col] =
                    acc[i][j][r];
}

__global__ __launch_bounds__(256) void k_combine8(const float* __restrict__ Pk,
                                                  float* __restrict__ Lg) {
    const size_t MM = (size_t)BATCH * CH * CH;
    size_t i = ((size_t)blockIdx.x * 256 + threadIdx.x) * 4;
    float4 s = *(const float4*)(Pk + i);
#pragma unroll
    for (int z = 1; z < 8; z++) {
        float4 v = *(const float4*)(Pk + z * MM + i);
        s.x += v.x; s.y += v.y; s.z += v.z; s.w += v.w;
    }
    *(float4*)(Lg + i) = s;
}

// softmax rows of 512 -> packed hi/lo bf16 in place
__global__ __launch_bounds__(256) void k_softmax_pack512(float* __restrict__ Lg) {
    __shared__ float buf[512];
    __shared__ float red[256];
    const int tid = threadIdx.x;
    float* row = Lg + (size_t)blockIdx.x * 512;
    float2 v = *(const float2*)(row + tid * 2);
    buf[tid * 2] = v.x;
    buf[tid * 2 + 1] = v.y;
    red[tid] = fmaxf(v.x, v.y);
    __syncthreads();
    for (int s = 128; s > 0; s >>= 1) {
        if (tid < s) red[tid] = fmaxf(red[tid], red[tid + s]);
        __syncthreads();
    }
    float m = red[0];
    __syncthreads();
    float e0 = __expf(buf[tid * 2] - m), e1 = __expf(buf[tid * 2 + 1] - m);
    buf[tid * 2] = e0;
    buf[tid * 2 + 1] = e1;
    red[tid] = e0 + e1;
    __syncthreads();
    for (int s = 128; s > 0; s >>= 1) {
        if (tid < s) red[tid] += red[tid + s];
        __syncthreads();
    }
    float inv = 1.0f / red[0];
    u16* u = (u16*)row;
    u16 h0, l0, h1, l1;
    split_bf16(buf[tid * 2] * inv, h0, l0);
    split_bf16(buf[tid * 2 + 1] * inv, h1, l1);
    __syncthreads();
    u[tid * 2] = h0;
    u[tid * 2 + 1] = h1;
    u[512 + tid * 2] = l0;
    u[512 + tid * 2 + 1] = l1;
}

// ---------------------------------------------------------------------------
// k3 MFMA (3-term): Y = A*pq + x. Epilogue writes Yhi/Ylo AND the transposed
// YT [n][c] via per-wave padded-LDS tiles — fused, no separate transpose.
// ---------------------------------------------------------------------------
__global__ __launch_bounds__(256, 2) void k3_mfma(const u16* __restrict__ Lu,
                                                  const u16* __restrict__ XT1hi,
                                                  const u16* __restrict__ XT1lo,
                                                  const float* __restrict__ X,
                                                  u16* __restrict__ Yhi,
                                                  u16* __restrict__ Ylo,
                                                  u16* __restrict__ YThi,
                                                  u16* __restrict__ YTlo) {
    __shared__ __align__(16) char smem[33280];  // 32KB staging; 2x(64x65 u32) transpose
    char* Ahi = smem;
    char* Alo = smem + 8192;
    char* Bhi = smem + 16384;
    char* Blo = smem + 24576;
    const int b = blockIdx.z;
    const u16* Au = Lu + (size_t)b * CH * 1024;
    const size_t boff = (size_t)b * CH * NSP;
    const float* Xb = X + boff;
    const int tid = threadIdx.x, lane = tid & 63, w = tid >> 6;
    const int wr = w >> 1, wc = w & 1;
    const int c0 = blockIdx.y * 128, n0 = blockIdx.x * 128;
    const int rl = lane >> 2;
    const int cb = (lane & 3) * 8;
    f32x4 acc[4][4];
#pragma unroll
    for (int i = 0; i < 4; i++)
#pragma unroll
        for (int j = 0; j < 4; j++) acc[i][j] = (f32x4){0.f, 0.f, 0.f, 0.f};

    for (int k0 = 0; k0 < CH; k0 += 32) {
#pragma unroll
        for (int s = 0; s < 2; s++) {
            int idx = w * 2 + s;
            int row = 16 * idx + rl;
            gload16(Au + (size_t)(c0 + row) * 1024 + k0 + cb, Ahi + idx * 1024);
            gload16(Au + (size_t)(c0 + row) * 1024 + 512 + k0 + cb, Alo + idx * 1024);
            gload16(XT1hi + boff + (size_t)(n0 + row) * CH + k0 + cb, Bhi + idx * 1024);
            gload16(XT1lo + boff + (size_t)(n0 + row) * CH + k0 + cb, Blo + idx * 1024);
        }
        __syncthreads();
        bfrag8 ah[4], al[4], bh[4], bl[4];
        const int q16 = (lane >> 4) * 16;
        const int l15 = (lane & 15);
#pragma unroll
        for (int i = 0; i < 4; i++) {
            int offa = (wr * 64 + i * 16 + l15) * 64 + q16;
            ah[i] = *(const bfrag8*)(Ahi + offa);
            al[i] = *(const bfrag8*)(Alo + offa);
            int offb = (wc * 64 + i * 16 + l15) * 64 + q16;
            bh[i] = *(const bfrag8*)(Bhi + offb);
            bl[i] = *(const bfrag8*)(Blo + offb);
        }
#pragma unroll
        for (int i = 0; i < 4; i++)
#pragma unroll
            for (int j = 0; j < 4; j++) {
                acc[i][j] = __builtin_amdgcn_mfma_f32_16x16x32_bf16(ah[i], bh[j], acc[i][j], 0, 0, 0);
                acc[i][j] = __builtin_amdgcn_mfma_f32_16x16x32_bf16(ah[i], bl[j], acc[i][j], 0, 0, 0);
                acc[i][j] = __builtin_amdgcn_mfma_f32_16x16x32_bf16(al[i], bh[j], acc[i][j], 0, 0, 0);
            }
        __syncthreads();
    }
    u16* Yhb = Yhi + boff;
    u16* Ylb = Ylo + boff;
    u16* YThb = YThi + boff;  // [n][c], same per-batch element count
    u16* YTlb = YTlo + boff;
    const int col = lane & 15, qr = (lane >> 4) * 4;
    unsigned int* Tb = (unsigned int*)smem;  // two 64x65 u32 wave-tiles
#pragma unroll
    for (int round = 0; round < 2; round++) {
        if (wr == round) {
            unsigned int* T = Tb + wc * 4160;
#pragma unroll
            for (int i = 0; i < 4; i++)
#pragma unroll
                for (int j = 0; j < 4; j++)
#pragma unroll
                    for (int r = 0; r < 4; r++) {
                        int cl = 16 * i + qr + r;       // c within wave tile
                        int nl = 16 * j + col;          // n within wave tile
                        int c = c0 + wr * 64 + cl;
                        int n = n0 + wc * 64 + nl;
                        float v = acc[i][j][r] + Xb[(size_t)c * NSP + n];
                        u16 h, l;
                        split_bf16(v, h, l);
                        Yhb[(size_t)c * NSP + n] = h;
                        Ylb[(size_t)c * NSP + n] = l;
                        T[nl * 65 + cl] = ((unsigned int)h << 16) | l;
                    }
        }
        __syncthreads();
        if (wr == round) {
            unsigned int* T = Tb + wc * 4160;
            const int cl = (lane & 15) * 4;
#pragma unroll
            for (int rep = 0; rep < 16; rep++) {
                int nq = rep * 4 + (lane >> 4);
                unsigned int p0 = T[nq * 65 + cl];
                unsigned int p1 = T[nq * 65 + cl + 1];
                unsigned int p2 = T[nq * 65 + cl + 2];
                unsigned int p3 = T[nq * 65 + cl + 3];
                ushort4 hv, lv;
                hv.x = p0 >> 16; hv.y = p1 >> 16; hv.z = p2 >> 16; hv.w = p3 >> 16;
                lv.x = p0 & 0xffff; lv.y = p1 & 0xffff; lv.z = p2 & 0xffff; lv.w = p3 & 0xffff;
                size_t o = (size_t)(n0 + wc * 64 + nq) * CH + c0 + wr * 64 + cl;
                *(ushort4*)(YThb + o) = hv;
                *(ushort4*)(YTlb + o) = lv;
            }
        }
        __syncthreads();
    }
}

// ---------------------------------------------------------------------------
// k4 MFMA symmetric (3-term) — R9: R7's triangular 128x128 / 4-wave / 64KB
// pipelined kernel (best measured: 71 us) + register fragment PREFETCH.
// R6's prefetch failed on the 512-thread 128-VGPR cap (spilled, +40MB HBM);
// at 256 threads __launch_bounds__(256,2) caps at 256 VGPR — frag sets
// ah0/bh0/ah1/bh1/al/bl (96 VGPR) + acc (64) + addressing fit (~190).
// Loop unrolled x2 with NAMED register sets (rule #20). Each phase's frag
// ds_reads issue inside the PREVIOUS phase's setprio/MFMA region, hiding
// their latency under 16 MFMAs + barrier:
//   P1(t) MMA(hh) prefetches al(t)        [after WAITB(10) -> U1(t)]
//   P2(t) MMA(lh) prefetches bl(t)        [after WAITB(12) -> U3(t)]
//   P3(t) MMA(hl) prefetches ah/bh(t+1)   [after WAITB(10) -> U0U2(t+1)]
// STAGE/WAITB ledger byte-identical to R7 (10/12/10; tails 10/8/4, 2/0/bare).
// WAR distances strictly larger than R7's (reads moved earlier). 
// ---------------------------------------------------------------------------
__global__ __launch_bounds__(256, 2) void k4_mfma(const u16* __restrict__ YThi0,
                                                  const u16* __restrict__ YTlo0,
                                                  float* __restrict__ S0) {
    __shared__ __align__(16) char smem[65536];
    const int tid = threadIdx.x, lane = tid & 63, w = tid >> 6;
    const int wr = w >> 1, wc = w & 1;  // 2x2 wave grid; wave tile 64x64
    const int rb = blockIdx.y;
    const u16* Phi = YThi0 + (size_t)rb * NSP * CH;
    const u16* Plo = YTlo0 + (size_t)rb * NSP * CH;
    float* S = S0 + (size_t)rb * NSP * NSP;
    int idx = blockIdx.x;
    int bi = (int)((sqrtf(8.f * (float)idx + 1.f) - 1.f) * 0.5f);
    while ((bi + 1) * (bi + 2) / 2 <= idx) bi++;
    while (bi * (bi + 1) / 2 > idx) bi--;
    int bj = idx - bi * (bi + 1) / 2;
    const int n0 = bi * 128, m0 = bj * 128;
    const bool diag = (bi == bj);

    const int rl = lane >> 2;        // staging row within 16-row chunk
    const int cb = (((lane & 3) ^ ((lane >> 3) & 3)) * 8);     // swizzled src chunk
    const int l15 = lane & 15;
    const int q16 = (((lane >> 4) ^ ((lane >> 1) & 3)) * 16);  // swizzled read slot

    // stage one 128x32 u16 unit (u: 0=Ahi,1=Alo,2=Bhi,3=Blo) into buf (kt&1)
    auto STAGE = [&](const u16* mat, int r0, int kt, int u) {
        char* dst = smem + (kt & 1) * 32768 + u * 8192;
        const int k0 = kt * 32;
#pragma unroll
        for (int s = 0; s < 2; s++) {
            int i2 = w * 2 + s;  // 8 chunks of 16 rows
            gload16(mat + (size_t)(r0 + i2 * 16 + rl) * CH + k0 + cb, dst + i2 * 1024);
        }
    };

    f32x4 acc[4][4];
#pragma unroll
    for (int i = 0; i < 4; i++)
#pragma unroll
        for (int j = 0; j < 4; j++) acc[i][j] = (f32x4){0.f, 0.f, 0.f, 0.f};
    bfrag8 ah0[4], bh0[4], ah1[4], bh1[4], al[4], bl[4];

    auto LDA = [&](const char* base, bfrag8* a) {
#pragma unroll
        for (int i = 0; i < 4; i++)
            a[i] = *(const bfrag8*)(base + (wr * 64 + i * 16 + l15) * 64 + q16);
    };
    auto LDB = [&](const char* base, bfrag8* bv) {
#pragma unroll
        for (int j = 0; j < 4; j++)
            bv[j] = *(const bfrag8*)(base + (wc * 64 + j * 16 + l15) * 64 + q16);
    };
    // MFMA burst; prefetch reads issued inside the setprio region so the
    // scheduler interleaves the independent ds_reads among the MFMAs.
    auto MMAp = [&](const bfrag8* a, const bfrag8* bv, auto pre) {
        __builtin_amdgcn_s_setprio(1);
        pre();
#pragma unroll
        for (int i = 0; i < 4; i++)
#pragma unroll
            for (int j = 0; j < 4; j++)
                acc[i][j] = __builtin_amdgcn_mfma_f32_16x16x32_bf16(a[i], bv[j], acc[i][j], 0, 0, 0);
        __builtin_amdgcn_s_setprio(0);
    };

#define WAITB(N)                                          \
    asm volatile("s_waitcnt vmcnt(" #N ")" ::: "memory"); \
    __builtin_amdgcn_sched_barrier(0);                    \
    __builtin_amdgcn_s_barrier();

    const char* b0 = smem;
    const char* b1 = smem + 32768;

    // prologue (R7 ledger)
    STAGE(Phi, n0, 0, 0);
    STAGE(Phi, m0, 0, 2);
    STAGE(Plo, n0, 0, 1);
    STAGE(Plo, m0, 0, 3);
    STAGE(Phi, n0, 1, 0);
    STAGE(Phi, m0, 1, 2);
    STAGE(Plo, n0, 1, 1);
    WAITB(10)
    // U0U2(0) landed: preload tile-0 hh fragments
    LDA(b0, ah0);
    LDB(b0 + 16384, bh0);

    for (int t = 0; t < 14; t += 2) {
        // ---- even tile t (buf0) ----
        STAGE(Plo, m0, t + 1, 3);
        WAITB(10)  // U1(t)
        MMAp(ah0, bh0, [&] { LDA(b0 + 8192, al); });
        STAGE(Phi, n0, t + 2, 0);
        STAGE(Phi, m0, t + 2, 2);
        WAITB(12)  // U3(t)
        MMAp(al, bh0, [&] { LDB(b0 + 24576, bl); });
        STAGE(Plo, n0, t + 2, 1);
        WAITB(10)  // U0U2(t+1)
        MMAp(ah0, bl, [&] {
            LDA(b1, ah1);
            LDB(b1 + 16384, bh1);
        });
        // ---- odd tile t+1 (buf1) ----
        STAGE(Plo, m0, t + 2, 3);
        WAITB(10)  // U1(t+1)
        MMAp(ah1, bh1, [&] { LDA(b1 + 8192, al); });
        STAGE(Phi, n0, t + 3, 0);
        STAGE(Phi, m0, t + 3, 2);
        WAITB(12)  // U3(t+1)
        MMAp(al, bh1, [&] { LDB(b1 + 24576, bl); });
        STAGE(Plo, n0, t + 3, 1);
        WAITB(10)  // U0U2(t+2)
        MMAp(ah1, bl, [&] {
            LDA(b0, ah0);
            LDB(b0 + 16384, bh0);
        });
    }
    {  // t = 14 (buf0): stage only U3(15); ah0/bh0 preloaded by P3(13)
        STAGE(Plo, m0, 15, 3);
        WAITB(10)  // U1(14)
        MMAp(ah0, bh0, [&] { LDA(b0 + 8192, al); });
        WAITB(8)   // U3(14)
        MMAp(al, bh0, [&] { LDB(b0 + 24576, bl); });
        WAITB(4)   // U0U2(15)
        MMAp(ah0, bl, [&] {
            LDA(b1, ah1);
            LDB(b1 + 16384, bh1);
        });
    }
    {  // t = 15 (buf1): drain
        WAITB(2)   // U1(15)
        MMAp(ah1, bh1, [&] { LDA(b1 + 8192, al); });
        WAITB(0)   // U3(15)
        MMAp(al, bh1, [&] { LDB(b1 + 24576, bl); });
        __builtin_amdgcn_sched_barrier(0);
        __builtin_amdgcn_s_barrier();
        MMAp(ah1, bl, [&] {});
    }
#undef WAITB

    const int col = lane & 15, qr = (lane >> 4) * 4;
#pragma unroll
    for (int i = 0; i < 4; i++)
#pragma unroll
        for (int j = 0; j < 4; j++)
#pragma unroll
            for (int r = 0; r < 4; r++)
                S[(size_t)(n0 + wr * 64 + 16 * i + qr + r) * NSP + m0 + wc * 64 + 16 * j + col] =
                    acc[i][j][r];
    if (!diag) {  // mirror tile via per-wave padded LDS transpose (old-k4 epilogue)
        float* Tbase = (float*)smem;
#pragma unroll
        for (int round = 0; round < 2; round++) {
            __syncthreads();
            if (wr == round) {
                float* T = Tbase + wc * (64 * 68);
#pragma unroll
                for (int i = 0; i < 4; i++)
#pragma unroll
                    for (int j = 0; j < 4; j++)
#pragma unroll
                        for (int r = 0; r < 4; r++)
                            T[(16 * j + col) * 68 + 16 * i + qr + r] = acc[i][j][r];
            }
            __syncthreads();
            if (wr == round) {
                float* T = Tbase + wc * (64 * 68);
                const int rq = (lane & 15) * 4;
#pragma unroll
                for (int rep = 0; rep < 16; rep++) {
                    int cq = rep * 4 + (lane >> 4);
                    float4 v = *(const float4*)(T + cq * 68 + rq);
                    *(float4*)(S + (size_t)(m0 + wc * 64 + cq) * NSP + n0 + wr * 64 + rq) = v;
                }
            }
        }
    }
}

// softmax rows of 4096 over contiguous S0|S1 (grid 8192); writes hi plane only
__global__ __launch_bounds__(256) void k_softmax_pack(float* __restrict__ S) {
    __shared__ float buf[4096];
    __shared__ float red[256];
    const int tid = threadIdx.x;
    float* row = S + (size_t)blockIdx.x * NSP;
    float m = -INFINITY;
#pragma unroll
    for (int it = 0; it < 4; it++) {
        int i = (tid + it * 256) * 4;
        float4 v = *(const float4*)(row + i);
        buf[i] = v.x; buf[i + 1] = v.y; buf[i + 2] = v.z; buf[i + 3] = v.w;
        m = fmaxf(m, fmaxf(fmaxf(v.x, v.y), fmaxf(v.z, v.w)));
    }
    red[tid] = m;
    __syncthreads();
    for (int s = 128; s > 0; s >>= 1) {
        if (tid < s) red[tid] = fmaxf(red[tid], red[tid + s]);
        __syncthreads();
    }
    m = red[0];
    __syncthreads();
    float sum = 0.f;
#pragma unroll
    for (int it = 0; it < 4; it++) {
        int i = (tid + it * 256) * 4;
        float e0 = __expf(buf[i] - m), e1 = __expf(buf[i + 1] - m);
        float e2 = __expf(buf[i + 2] - m), e3 = __expf(buf[i + 3] - m);
        buf[i] = e0; buf[i + 1] = e1; buf[i + 2] = e2; buf[i + 3] = e3;
        sum += e0 + e1 + e2 + e3;
    }
    red[tid] = sum;
    __syncthreads();
    for (int s = 128; s > 0; s >>= 1) {
        if (tid < s) red[tid] += red[tid + s];
        __syncthreads();
    }
    float inv = 1.0f / red[0];
    u16* u = (u16*)row;
#pragma unroll
    for (int it = 0; it < 4; it++) {
        int i = (tid + it * 256) * 4;
        ushort4 hv;
        hv.x = (u16)(__float_as_uint(buf[i] * inv) >> 16);
        hv.y = (u16)(__float_as_uint(buf[i + 1] * inv) >> 16);
        hv.z = (u16)(__float_as_uint(buf[i + 2] * inv) >> 16);
        hv.w = (u16)(__float_as_uint(buf[i + 3] * inv) >> 16);
        *(ushort4*)(u + i) = hv;
    }
}

// ---------------------------------------------------------------------------
// k6 MFMA 1-term, split-K=2, 2 batches/launch — pipelined, single barrier
// per phase (unchanged; passing).
// ---------------------------------------------------------------------------
__global__ __launch_bounds__(512, 2) void k6_mfma(const u16* __restrict__ Yhi0,
                                                  const u16* __restrict__ Ylo0,
                                                  const u16* __restrict__ Su,
                                                  float* __restrict__ Out0,
                                                  float* __restrict__ Pp0,
                                                  float* __restrict__ Pp1) {
    __shared__ __align__(16) char smem[73728];  // 3 x (8KB A + 16KB B)
    const int tid = threadIdx.x, lane = tid & 63, w = tid >> 6;
    const int wr = w >> 2, wc = w & 3;  // 2(c) x 4(m); wave tile 64x64
    const int m0 = blockIdx.x * 256, c0 = blockIdx.y * 128;
    const int rb = blockIdx.z >> 1, kz = blockIdx.z & 1;
    const u16* Yhi = Yhi0 + (size_t)rb * CH * NSP;
    const u16* Ylo = Ylo0 + (size_t)rb * CH * NSP;
    const u16* Pu = Su + (size_t)rb * NSP * NSP * 2;  // S batch stride in u16 units
    float* Out = Out0 + (size_t)rb * CH * NSP;
    float* Ppart = rb ? Pp1 : Pp0;
    const int kb = kz * 2048;
    const int rl = lane >> 2;
    const int cb = (((lane & 3) ^ ((lane >> 3) & 3)) * 8);     // swizzled src chunk
    const int l15 = lane & 15;
    const int q16 = (((lane >> 4) ^ ((lane >> 1) & 3)) * 16);  // swizzled read slot

    // stage K-tile kt into slot: A = Yhi[c0..+128][32], B = Pu[m0..+256][32]
    auto STAGE = [&](int kt, int slot) {
        char* dst = smem + slot * 24576;
        const int k0 = kb + kt * 32;
        gload16(Yhi + (size_t)(c0 + w * 16 + rl) * NSP + k0 + cb, dst + w * 1024);
#pragma unroll
        for (int s = 0; s < 2; s++) {
            int idx = w * 2 + s;
            gload16(Pu + (size_t)(m0 + idx * 16 + rl) * 8192 + k0 + cb,
                    dst + 8192 + idx * 1024);
        }
    };

    f32x4 acc[4][4];
#pragma unroll
    for (int i = 0; i < 4; i++)
#pragma unroll
        for (int j = 0; j < 4; j++) acc[i][j] = (f32x4){0.f, 0.f, 0.f, 0.f};
    bfrag8 ah[4], bh[4];

#define K6PHASE(SLOT, STSLOT, T, DOSTAGE, WN)                                            \
    {                                                                                    \
        const char* bA = smem + (SLOT)*24576;                                            \
        const char* bB = bA + 8192;                                                      \
        _Pragma("unroll") for (int i = 0; i < 4; i++) ah[i] =                            \
            *(const bfrag8*)(bA + (wr * 64 + i * 16 + l15) * 64 + q16);                  \
        _Pragma("unroll") for (int j = 0; j < 4; j++) bh[j] =                            \
            *(const bfrag8*)(bB + (wc * 64 + j * 16 + l15) * 64 + q16);                  \
        if (DOSTAGE) STAGE((T) + 2, (STSLOT));                                           \
        asm volatile("s_waitcnt vmcnt(" #WN ")" ::: "memory");                           \
        __builtin_amdgcn_sched_barrier(0);                                               \
        __builtin_amdgcn_s_barrier();                                                    \
        __builtin_amdgcn_s_setprio(1);                                                   \
        _Pragma("unroll") for (int i = 0; i < 4; i++)                                    \
            _Pragma("unroll") for (int j = 0; j < 4; j++) acc[i][j] =                    \
                __builtin_amdgcn_mfma_f32_16x16x32_bf16(ah[i], bh[j], acc[i][j], 0, 0, 0); \
        __builtin_amdgcn_s_setprio(0);                                                   \
    }

    // prologue: tiles 0,1 in flight; wait tile 0
    STAGE(0, 0);
    STAGE(1, 1);
    asm volatile("s_waitcnt vmcnt(3)" ::: "memory");
    __builtin_amdgcn_sched_barrier(0);
    __builtin_amdgcn_s_barrier();

    for (int tt = 0; tt < 60; tt += 3) {
        K6PHASE(0, 2, tt, true, 3)
        K6PHASE(1, 0, tt + 1, true, 3)
        K6PHASE(2, 1, tt + 2, true, 3)
    }
    K6PHASE(0, 2, 60, true, 3)   // stages 62 -> slot 2
    K6PHASE(1, 0, 61, true, 3)   // stages 63 -> slot 0
    K6PHASE(2, 0, 62, false, 0)  // drain: tile 63 landed
    K6PHASE(0, 0, 63, false, 0)
#undef K6PHASE

    const int col = lane & 15, qr = (lane >> 4) * 4;
    if (kz == 0) {
#pragma unroll
        for (int i = 0; i < 4; i++)
#pragma unroll
            for (int j = 0; j < 4; j++)
#pragma unroll
                for (int r = 0; r < 4; r++) {
                    int c = c0 + wr * 64 + 16 * i + qr + r;
                    int mm = m0 + wc * 64 + 16 * j + col;
                    Out[(size_t)c * NSP + mm] =
                        acc[i][j][r] +
                        join_bf16(Yhi[(size_t)c * NSP + mm], Ylo[(size_t)c * NSP + mm]);
                }
    } else {
#pragma unroll
        for (int i = 0; i < 4; i++)
#pragma unroll
            for (int j = 0; j < 4; j++)
#pragma unroll
                for (int r = 0; r < 4; r++) {
                    int c = c0 + wr * 64 + 16 * i + qr + r;
                    int mm = m0 + wc * 64 + 16 * j + col;
                    Ppart[(size_t)c * NSP + mm] = acc[i][j][r];
                }
    }
}

// out[b] += Ppart[b] for the round's 2 batches
__global__ __launch_bounds__(256) void k_fixup(float* __restrict__ Out0,
                                               const float* __restrict__ Pp0,
                                               const float* __restrict__ Pp1) {
    const size_t CN = (size_t)CH * NSP;
    const int b = blockIdx.y;
    const float* P = b ? Pp1 : Pp0;
    float* O = Out0 + (size_t)b * CN;
    size_t i = ((size_t)blockIdx.x * 256 + threadIdx.x) * 4;
    float4 o = *(const float4*)(O + i);
    float4 a = *(const float4*)(P + i);
    o.x += a.x; o.y += a.y; o.z += a.z; o.w += a.w;
    *(float4*)(O + i) = o;
}

extern "C" void kernel_launch(void* const* d_in, const int* in_sizes, int n_in,
                              void* d_out, int out_size, void* d_ws, size_t ws_size,
                              hipStream_t stream) {
    const float* x = (const float*)d_in[0];
    float* out = (float*)d_out;

    // workspace layout (196 MB):
    //   [0,128MB): S0|S1 fp32 score buffers; aliased by X-prep [0,96MB) (dead after k3)
    //   [128,192MB): Yhi|Ylo|YThi|YTlo (YT per-batch 4MB slices)
    //       Pk (k1 partials, 32MB) aliases Yhi|Ylo (dead before k3)
    //       k6 round-r partials alias the YT slices of round r's batches (dead after k4)
    //   [192,196MB): Lg
    char* p = (char*)d_ws;
    const size_t SZ16 = (size_t)BATCH * CH * NSP * 2;  // 16 MB
    const size_t HALF = SZ16 / 2;                      // 8 MB = CH*NSP*4
    u16* XHi = (u16*)p;
    u16* XLo = (u16*)(p + SZ16);
    u16* XT2hi = (u16*)(p + 2 * SZ16);
    u16* XT2lo = (u16*)(p + 3 * SZ16);
    u16* XT1hi = (u16*)(p + 4 * SZ16);
    u16* XT1lo = (u16*)(p + 5 * SZ16);
    float* S = (float*)p;
    u16* Yhi = (u16*)(p + 8 * SZ16);
    u16* Ylo = (u16*)(p + 9 * SZ16);
    u16* YThi = (u16*)(p + 10 * SZ16);
    u16* YTlo = (u16*)(p + 11 * SZ16);
    float* Pk = (float*)(p + 8 * SZ16);
    float* Lg = (float*)(p + 12 * SZ16);

    // Stage 1: channel attention
    k_prep_cn<<<dim3(NSP / 64, CH / 64, BATCH), 256, 0, stream>>>(x, XHi, XLo, XT1hi, XT1lo);
    k_prep_nc<<<dim3(NSP / 64, CH / 64, BATCH), 256, 0, stream>>>(x, XT2hi, XT2lo);
    k1_mfma<<<dim3(512), 256, 0, stream>>>(XHi, XLo, XT2hi, XT2lo, Pk);
    k_combine8<<<dim3((BATCH * CH * CH) / (4 * 256)), 256, 0, stream>>>(Pk, Lg);
    k_softmax_pack512<<<dim3(BATCH * CH), 256, 0, stream>>>(Lg);
    k3_mfma<<<dim3(NSP / 128, CH / 128, BATCH), 256, 0, stream>>>((const u16*)Lg, XT1hi, XT1lo, x,
                                                                  Yhi, Ylo, YThi, YTlo);

    // Stage 2: positional attention, 2 batches per round
    const int TRI = (NSP / 128) * (NSP / 128 + 1) / 2;  // 528
    for (int round = 0; round < 2; round++) {
        const size_t b0 = (size_t)(2 * round);
        float* Pp0 = (float*)((char*)YThi + round * HALF);
        float* Pp1 = (float*)((char*)YTlo + round * HALF);
        k4_mfma<<<dim3(TRI, 2), 256, 0, stream>>>(YThi + b0 * NSP * CH, YTlo + b0 * NSP * CH, S);
        k_softmax_pack<<<dim3(2 * NSP), 256, 0, stream>>>(S);
        k6_mfma<<<dim3(NSP / 256, CH / 128, 4), 512, 0, stream>>>(Yhi + b0 * CH * NSP,
                                                                  Ylo + b0 * CH * NSP,
                                                                  (const u16*)S,
                                                                  out + b0 * CH * NSP, Pp0, Pp1);
        k_fixup<<<dim3((CH * NSP) / (4 * 256), 2), 256, 0, stream>>>(out + b0 * CH * NSP, Pp0, Pp1);
    }
}

// Round 11
// 462.811 us; speedup vs baseline: 1.0165x; 1.0046x over previous
//
#include <hip/hip_runtime.h>

#define BATCH 4
#define CH 512
#define NSP 4096   // 64*64 spatial

typedef __attribute__((ext_vector_type(8))) short bfrag8;  // 8 bf16 (4 VGPRs)
typedef __attribute__((ext_vector_type(4))) float f32x4;
typedef unsigned short u16;

#define AS1 __attribute__((address_space(1)))
#define AS3 __attribute__((address_space(3)))
__device__ __forceinline__ void gload16(const void* g, void* l) {
    __builtin_amdgcn_global_load_lds((const AS1 void*)g, (AS3 void*)l, 16, 0, 0);
}

__device__ __forceinline__ void split_bf16(float y, u16& h, u16& l) {
    unsigned int u = __float_as_uint(y);
    h = (u16)(u >> 16);
    float r = y - __uint_as_float(((unsigned int)h) << 16);
    l = (u16)(__float_as_uint(r) >> 16);
}
__device__ __forceinline__ float join_bf16(u16 h, u16 l) {
    return __uint_as_float(((unsigned int)h) << 16) + __uint_as_float(((unsigned int)l) << 16);
}

// ---------------------------------------------------------------------------
// prep 1: x [C][N] view -> XHi/XLo (same layout) + XT1 [n][c] (transpose)
// ---------------------------------------------------------------------------
__global__ __launch_bounds__(256) void k_prep_cn(const float* __restrict__ X,
                                                 u16* __restrict__ XHi,
                                                 u16* __restrict__ XLo,
                                                 u16* __restrict__ XT1hi,
                                                 u16* __restrict__ XT1lo) {
    __shared__ unsigned int t[64][65];
    const size_t boff = (size_t)blockIdx.z * CH * NSP;
    const int c0 = blockIdx.y * 64, n0 = blockIdx.x * 64;
    const int r = threadIdx.x >> 4, col4 = (threadIdx.x & 15) * 4;
#pragma unroll
    for (int it = 0; it < 4; it++) {
        int rl = r + it * 16;
        float4 v = *(const float4*)(X + boff + (size_t)(c0 + rl) * NSP + n0 + col4);
        ushort4 h, l;
        split_bf16(v.x, h.x, l.x);
        split_bf16(v.y, h.y, l.y);
        split_bf16(v.z, h.z, l.z);
        split_bf16(v.w, h.w, l.w);
        *(ushort4*)(XHi + boff + (size_t)(c0 + rl) * NSP + n0 + col4) = h;
        *(ushort4*)(XLo + boff + (size_t)(c0 + rl) * NSP + n0 + col4) = l;
        t[rl][col4 + 0] = ((unsigned int)h.x << 16) | l.x;
        t[rl][col4 + 1] = ((unsigned int)h.y << 16) | l.y;
        t[rl][col4 + 2] = ((unsigned int)h.z << 16) | l.z;
        t[rl][col4 + 3] = ((unsigned int)h.w << 16) | l.w;
    }
    __syncthreads();
#pragma unroll
    for (int it = 0; it < 4; it++) {
        int cl = r + it * 16;
        unsigned int p0 = t[col4 + 0][cl];
        unsigned int p1 = t[col4 + 1][cl];
        unsigned int p2 = t[col4 + 2][cl];
        unsigned int p3 = t[col4 + 3][cl];
        ushort4 hv, lv;
        hv.x = p0 >> 16; hv.y = p1 >> 16; hv.z = p2 >> 16; hv.w = p3 >> 16;
        lv.x = p0 & 0xffff; lv.y = p1 & 0xffff; lv.z = p2 & 0xffff; lv.w = p3 & 0xffff;
        *(ushort4*)(XT1hi + boff + (size_t)(n0 + cl) * CH + c0 + col4) = hv;
        *(ushort4*)(XT1lo + boff + (size_t)(n0 + cl) * CH + c0 + col4) = lv;
    }
}

// prep 2: x [N][C] view -> XT2 [d][n] (transpose)
__global__ __launch_bounds__(256) void k_prep_nc(const float* __restrict__ X,
                                                 u16* __restrict__ XT2hi,
                                                 u16* __restrict__ XT2lo) {
    __shared__ unsigned int t[64][65];
    const size_t boff = (size_t)blockIdx.z * CH * NSP;
    const int n0 = blockIdx.x * 64, d0 = blockIdx.y * 64;
    const int r = threadIdx.x >> 4, col4 = (threadIdx.x & 15) * 4;
#pragma unroll
    for (int it = 0; it < 4; it++) {
        int rl = r + it * 16;
        float4 v = *(const float4*)(X + boff + (size_t)(n0 + rl) * CH + d0 + col4);
        ushort4 h, l;
        split_bf16(v.x, h.x, l.x);
        split_bf16(v.y, h.y, l.y);
        split_bf16(v.z, h.z, l.z);
        split_bf16(v.w, h.w, l.w);
        t[rl][col4 + 0] = ((unsigned int)h.x << 16) | l.x;
        t[rl][col4 + 1] = ((unsigned int)h.y << 16) | l.y;
        t[rl][col4 + 2] = ((unsigned int)h.z << 16) | l.z;
        t[rl][col4 + 3] = ((unsigned int)h.w << 16) | l.w;
    }
    __syncthreads();
#pragma unroll
    for (int it = 0; it < 4; it++) {
        int cl = r + it * 16;
        unsigned int p0 = t[col4 + 0][cl];
        unsigned int p1 = t[col4 + 1][cl];
        unsigned int p2 = t[col4 + 2][cl];
        unsigned int p3 = t[col4 + 3][cl];
        ushort4 hv, lv;
        hv.x = p0 >> 16; hv.y = p1 >> 16; hv.z = p2 >> 16; hv.w = p3 >> 16;
        lv.x = p0 & 0xffff; lv.y = p1 & 0xffff; lv.z = p2 & 0xffff; lv.w = p3 & 0xffff;
        *(ushort4*)(XT2hi + boff + (size_t)(d0 + cl) * NSP + n0 + col4) = hv;
        *(ushort4*)(XT2lo + boff + (size_t)(d0 + cl) * NSP + n0 + col4) = lv;
    }
}

// ---------------------------------------------------------------------------
// k1 MFMA split-K=8 with XCD swizzle — R10: ported to the R7-proven pipelined
// schedule (identical shape: 128-tile, 4 waves, 4 units x 2-load STAGE,
// exactly 16 K-tiles of 32 per kz slice). Counted vmcnt, single barrier per
// phase, setprio, both-sides XOR swizzle. LDS 64KB dbuf -> 2 blocks/CU.
// Ledger (= R7 k4): prologue 14 loads, vmcnt(10)->U0U2(0);
//   P1(t): +U3(t+1), vmcnt(10)->U1(t); P2(t): +U0U2(t+2), vmcnt(12)->U3(t)
//   P3(t): +U1(t+2), vmcnt(10)->U0U2(t+1); t=14: 10/8/4; t=15: 2/0/bare
// ---------------------------------------------------------------------------
__global__ __launch_bounds__(256, 2) void k1_mfma(const u16* __restrict__ XHi,
                                                  const u16* __restrict__ XLo,
                                                  const u16* __restrict__ XT2hi,
                                                  const u16* __restrict__ XT2lo,
                                                  float* __restrict__ Pk) {
    __shared__ __align__(16) char smem[65536];
    const int bid = blockIdx.x;
    const int xcd = bid & 7;
    const int i1 = bid >> 3;
    const int group = xcd * 4 + (i1 >> 4);
    const int b = group >> 3, kz = group & 7;
    const int tile = i1 & 15;
    const int c0 = (tile >> 2) * 128, d0 = (tile & 3) * 128;
    const size_t boff = (size_t)b * CH * NSP;
    const int tid = threadIdx.x, lane = tid & 63, w = tid >> 6;
    const int wr = w >> 1, wc = w & 1;
    const int rl = lane >> 2;
    const int cb = (((lane & 3) ^ ((lane >> 3) & 3)) * 8);     // swizzled src chunk
    const int l15 = lane & 15;
    const int q16 = (((lane >> 4) ^ ((lane >> 1) & 3)) * 16);  // swizzled read slot
    const int kbeg = kz * 512;

    // stage one 128x32 u16 unit (u: 0=Ahi,1=Alo,2=Bhi,3=Blo) into buf (kt&1)
    auto STAGE = [&](const u16* mat, int r0, int kt, int u) {
        char* dst = smem + (kt & 1) * 32768 + u * 8192;
        const int k0 = kbeg + kt * 32;
#pragma unroll
        for (int s = 0; s < 2; s++) {
            int i2 = w * 2 + s;
            gload16(mat + boff + (size_t)(r0 + i2 * 16 + rl) * NSP + k0 + cb, dst + i2 * 1024);
        }
    };

    f32x4 acc[4][4];
#pragma unroll
    for (int i = 0; i < 4; i++)
#pragma unroll
        for (int j = 0; j < 4; j++) acc[i][j] = (f32x4){0.f, 0.f, 0.f, 0.f};
    bfrag8 ah[4], al[4], bh[4], bl[4];

    auto LDA = [&](const char* base, bfrag8* a) {
#pragma unroll
        for (int i = 0; i < 4; i++)
            a[i] = *(const bfrag8*)(base + (wr * 64 + i * 16 + l15) * 64 + q16);
    };
    auto LDB = [&](const char* base, bfrag8* bv) {
#pragma unroll
        for (int j = 0; j < 4; j++)
            bv[j] = *(const bfrag8*)(base + (wc * 64 + j * 16 + l15) * 64 + q16);
    };
    auto MMA = [&](const bfrag8* a, const bfrag8* bv) {
        __builtin_amdgcn_s_setprio(1);
#pragma unroll
        for (int i = 0; i < 4; i++)
#pragma unroll
            for (int j = 0; j < 4; j++)
                acc[i][j] = __builtin_amdgcn_mfma_f32_16x16x32_bf16(a[i], bv[j], acc[i][j], 0, 0, 0);
        __builtin_amdgcn_s_setprio(0);
    };

#define WAITB(N)                                          \
    asm volatile("s_waitcnt vmcnt(" #N ")" ::: "memory"); \
    __builtin_amdgcn_sched_barrier(0);                    \
    __builtin_amdgcn_s_barrier();

    // prologue (R7 ledger)
    STAGE(XHi, c0, 0, 0);
    STAGE(XT2hi, d0, 0, 2);
    STAGE(XLo, c0, 0, 1);
    STAGE(XT2lo, d0, 0, 3);
    STAGE(XHi, c0, 1, 0);
    STAGE(XT2hi, d0, 1, 2);
    STAGE(XLo, c0, 1, 1);
    WAITB(10)

    for (int t = 0; t < 14; ++t) {
        const char* buf = smem + (t & 1) * 32768;
        // P1: hh
        LDA(buf, ah);
        LDB(buf + 16384, bh);
        STAGE(XT2lo, d0, t + 1, 3);
        WAITB(10)
        MMA(ah, bh);
        // P2: lh
        LDA(buf + 8192, al);
        STAGE(XHi, c0, t + 2, 0);
        STAGE(XT2hi, d0, t + 2, 2);
        WAITB(12)
        MMA(al, bh);
        // P3: hl
        LDB(buf + 24576, bl);
        STAGE(XLo, c0, t + 2, 1);
        WAITB(10)
        MMA(ah, bl);
    }
    {  // t = 14 (buf0): stage only U3(15)
        const char* buf = smem;
        LDA(buf, ah);
        LDB(buf + 16384, bh);
        STAGE(XT2lo, d0, 15, 3);
        WAITB(10)
        MMA(ah, bh);
        LDA(buf + 8192, al);
        WAITB(8)
        MMA(al, bh);
        LDB(buf + 24576, bl);
        WAITB(4)
        MMA(ah, bl);
    }
    {  // t = 15 (buf1): no staging, drain
        const char* buf = smem + 32768;
        LDA(buf, ah);
        LDB(buf + 16384, bh);
        WAITB(2)
        MMA(ah, bh);
        LDA(buf + 8192, al);
        WAITB(0)
        MMA(al, bh);
        LDB(buf + 24576, bl);
        __builtin_amdgcn_sched_barrier(0);
        __builtin_amdgcn_s_barrier();
        MMA(ah, bl);
    }
#undef WAITB

    float* Lb = Pk + (size_t)kz * BATCH * CH * CH + (size_t)b * CH * CH;
    const int col = lane & 15, qr = (lane >> 4) * 4;
#pragma unroll
    for (int i = 0; i < 4; i++)
#pragma unroll
        for (int j = 0; j < 4; j++)
#pragma unroll
            for (int r = 0; r < 4; r++)
                Lb[(size_t)(c0 + wr * 64 + 16 * i + qr + r) * CH + d0 + wc * 64 + 16 * j + col] =
                    acc[i][j][r];
}

__global__ __launch_bounds__(256) void k_combine8(const float* __restrict__ Pk,
                                                  float* __restrict__ Lg) {
    const size_t MM = (size_t)BATCH * CH * CH;
    size_t i = ((size_t)blockIdx.x * 256 + threadIdx.x) * 4;
    float4 s = *(const float4*)(Pk + i);
#pragma unroll
    for (int z = 1; z < 8; z++) {
        float4 v = *(const float4*)(Pk + z * MM + i);
        s.x += v.x; s.y += v.y; s.z += v.z; s.w += v.w;
    }
    *(float4*)(Lg + i) = s;
}

// softmax rows of 512 -> packed hi/lo bf16 in place
__global__ __launch_bounds__(256) void k_softmax_pack512(float* __restrict__ Lg) {
    __shared__ float buf[512];
    __shared__ float red[256];
    const int tid = threadIdx.x;
    float* row = Lg + (size_t)blockIdx.x * 512;
    float2 v = *(const float2*)(row + tid * 2);
    buf[tid * 2] = v.x;
    buf[tid * 2 + 1] = v.y;
    red[tid] = fmaxf(v.x, v.y);
    __syncthreads();
    for (int s = 128; s > 0; s >>= 1) {
        if (tid < s) red[tid] = fmaxf(red[tid], red[tid + s]);
        __syncthreads();
    }
    float m = red[0];
    __syncthreads();
    float e0 = __expf(buf[tid * 2] - m), e1 = __expf(buf[tid * 2 + 1] - m);
    buf[tid * 2] = e0;
    buf[tid * 2 + 1] = e1;
    red[tid] = e0 + e1;
    __syncthreads();
    for (int s = 128; s > 0; s >>= 1) {
        if (tid < s) red[tid] += red[tid + s];
        __syncthreads();
    }
    float inv = 1.0f / red[0];
    u16* u = (u16*)row;
    u16 h0, l0, h1, l1;
    split_bf16(buf[tid * 2] * inv, h0, l0);
    split_bf16(buf[tid * 2 + 1] * inv, h1, l1);
    __syncthreads();
    u[tid * 2] = h0;
    u[tid * 2 + 1] = h1;
    u[512 + tid * 2] = l0;
    u[512 + tid * 2 + 1] = l1;
}

// ---------------------------------------------------------------------------
// k3 MFMA (3-term): Y = A*pq + x. Epilogue writes Yhi/Ylo AND the transposed
// YT [n][c] via per-wave padded-LDS tiles — fused, no separate transpose.
// ---------------------------------------------------------------------------
__global__ __launch_bounds__(256, 2) void k3_mfma(const u16* __restrict__ Lu,
                                                  const u16* __restrict__ XT1hi,
                                                  const u16* __restrict__ XT1lo,
                                                  const float* __restrict__ X,
                                                  u16* __restrict__ Yhi,
                                                  u16* __restrict__ Ylo,
                                                  u16* __restrict__ YThi,
                                                  u16* __restrict__ YTlo) {
    __shared__ __align__(16) char smem[33280];  // 32KB staging; 2x(64x65 u32) transpose
    char* Ahi = smem;
    char* Alo = smem + 8192;
    char* Bhi = smem + 16384;
    char* Blo = smem + 24576;
    const int b = blockIdx.z;
    const u16* Au = Lu + (size_t)b * CH * 1024;
    const size_t boff = (size_t)b * CH * NSP;
    const float* Xb = X + boff;
    const int tid = threadIdx.x, lane = tid & 63, w = tid >> 6;
    const int wr = w >> 1, wc = w & 1;
    const int c0 = blockIdx.y * 128, n0 = blockIdx.x * 128;
    const int rl = lane >> 2;
    const int cb = (lane & 3) * 8;
    f32x4 acc[4][4];
#pragma unroll
    for (int i = 0; i < 4; i++)
#pragma unroll
        for (int j = 0; j < 4; j++) acc[i][j] = (f32x4){0.f, 0.f, 0.f, 0.f};

    for (int k0 = 0; k0 < CH; k0 += 32) {
#pragma unroll
        for (int s = 0; s < 2; s++) {
            int idx = w * 2 + s;
            int row = 16 * idx + rl;
            gload16(Au + (size_t)(c0 + row) * 1024 + k0 + cb, Ahi + idx * 1024);
            gload16(Au + (size_t)(c0 + row) * 1024 + 512 + k0 + cb, Alo + idx * 1024);
            gload16(XT1hi + boff + (size_t)(n0 + row) * CH + k0 + cb, Bhi + idx * 1024);
            gload16(XT1lo + boff + (size_t)(n0 + row) * CH + k0 + cb, Blo + idx * 1024);
        }
        __syncthreads();
        bfrag8 ah[4], al[4], bh[4], bl[4];
        const int q16 = (lane >> 4) * 16;
        const int l15 = (lane & 15);
#pragma unroll
        for (int i = 0; i < 4; i++) {
            int offa = (wr * 64 + i * 16 + l15) * 64 + q16;
            ah[i] = *(const bfrag8*)(Ahi + offa);
            al[i] = *(const bfrag8*)(Alo + offa);
            int offb = (wc * 64 + i * 16 + l15) * 64 + q16;
            bh[i] = *(const bfrag8*)(Bhi + offb);
            bl[i] = *(const bfrag8*)(Blo + offb);
        }
#pragma unroll
        for (int i = 0; i < 4; i++)
#pragma unroll
            for (int j = 0; j < 4; j++) {
                acc[i][j] = __builtin_amdgcn_mfma_f32_16x16x32_bf16(ah[i], bh[j], acc[i][j], 0, 0, 0);
                acc[i][j] = __builtin_amdgcn_mfma_f32_16x16x32_bf16(ah[i], bl[j], acc[i][j], 0, 0, 0);
                acc[i][j] = __builtin_amdgcn_mfma_f32_16x16x32_bf16(al[i], bh[j], acc[i][j], 0, 0, 0);
            }
        __syncthreads();
    }
    u16* Yhb = Yhi + boff;
    u16* Ylb = Ylo + boff;
    u16* YThb = YThi + boff;  // [n][c], same per-batch element count
    u16* YTlb = YTlo + boff;
    const int col = lane & 15, qr = (lane >> 4) * 4;
    unsigned int* Tb = (unsigned int*)smem;  // two 64x65 u32 wave-tiles
#pragma unroll
    for (int round = 0; round < 2; round++) {
        if (wr == round) {
            unsigned int* T = Tb + wc * 4160;
#pragma unroll
            for (int i = 0; i < 4; i++)
#pragma unroll
                for (int j = 0; j < 4; j++)
#pragma unroll
                    for (int r = 0; r < 4; r++) {
                        int cl = 16 * i + qr + r;       // c within wave tile
                        int nl = 16 * j + col;          // n within wave tile
                        int c = c0 + wr * 64 + cl;
                        int n = n0 + wc * 64 + nl;
                        float v = acc[i][j][r] + Xb[(size_t)c * NSP + n];
                        u16 h, l;
                        split_bf16(v, h, l);
                        Yhb[(size_t)c * NSP + n] = h;
                        Ylb[(size_t)c * NSP + n] = l;
                        T[nl * 65 + cl] = ((unsigned int)h << 16) | l;
                    }
        }
        __syncthreads();
        if (wr == round) {
            unsigned int* T = Tb + wc * 4160;
            const int cl = (lane & 15) * 4;
#pragma unroll
            for (int rep = 0; rep < 16; rep++) {
                int nq = rep * 4 + (lane >> 4);
                unsigned int p0 = T[nq * 65 + cl];
                unsigned int p1 = T[nq * 65 + cl + 1];
                unsigned int p2 = T[nq * 65 + cl + 2];
                unsigned int p3 = T[nq * 65 + cl + 3];
                ushort4 hv, lv;
                hv.x = p0 >> 16; hv.y = p1 >> 16; hv.z = p2 >> 16; hv.w = p3 >> 16;
                lv.x = p0 & 0xffff; lv.y = p1 & 0xffff; lv.z = p2 & 0xffff; lv.w = p3 & 0xffff;
                size_t o = (size_t)(n0 + wc * 64 + nq) * CH + c0 + wr * 64 + cl;
                *(ushort4*)(YThb + o) = hv;
                *(ushort4*)(YTlb + o) = lv;
            }
        }
        __syncthreads();
    }
}

// ---------------------------------------------------------------------------
// k4 MFMA symmetric (3-term) — R9 kernel (triangular 128x128, 4 waves, 64KB,
// pipelined + register prefetch) + R10: XCD-chunked triangular swizzle.
// TRI = 528 = 8*66 exactly -> idx = (bid&7)*66 + (bid>>3) is bijective and
// gives each XCD a contiguous triangular range (consecutive (bi,bj) share
// the bi row-panel -> L2 reuse within the XCD despite the S-write stream).
// ---------------------------------------------------------------------------
__global__ __launch_bounds__(256, 2) void k4_mfma(const u16* __restrict__ YThi0,
                                                  const u16* __restrict__ YTlo0,
                                                  float* __restrict__ S0) {
    __shared__ __align__(16) char smem[65536];
    const int tid = threadIdx.x, lane = tid & 63, w = tid >> 6;
    const int wr = w >> 1, wc = w & 1;  // 2x2 wave grid; wave tile 64x64
    const int rb = blockIdx.y;
    const u16* Phi = YThi0 + (size_t)rb * NSP * CH;
    const u16* Plo = YTlo0 + (size_t)rb * NSP * CH;
    float* S = S0 + (size_t)rb * NSP * NSP;
    const int bid0 = blockIdx.x;
    int idx = (bid0 & 7) * 66 + (bid0 >> 3);  // XCD-chunked, bijective (528=8*66)
    int bi = (int)((sqrtf(8.f * (float)idx + 1.f) - 1.f) * 0.5f);
    while ((bi + 1) * (bi + 2) / 2 <= idx) bi++;
    while (bi * (bi + 1) / 2 > idx) bi--;
    int bj = idx - bi * (bi + 1) / 2;
    const int n0 = bi * 128, m0 = bj * 128;
    const bool diag = (bi == bj);

    const int rl = lane >> 2;        // staging row within 16-row chunk
    const int cb = (((lane & 3) ^ ((lane >> 3) & 3)) * 8);     // swizzled src chunk
    const int l15 = lane & 15;
    const int q16 = (((lane >> 4) ^ ((lane >> 1) & 3)) * 16);  // swizzled read slot

    // stage one 128x32 u16 unit (u: 0=Ahi,1=Alo,2=Bhi,3=Blo) into buf (kt&1)
    auto STAGE = [&](const u16* mat, int r0, int kt, int u) {
        char* dst = smem + (kt & 1) * 32768 + u * 8192;
        const int k0 = kt * 32;
#pragma unroll
        for (int s = 0; s < 2; s++) {
            int i2 = w * 2 + s;  // 8 chunks of 16 rows
            gload16(mat + (size_t)(r0 + i2 * 16 + rl) * CH + k0 + cb, dst + i2 * 1024);
        }
    };

    f32x4 acc[4][4];
#pragma unroll
    for (int i = 0; i < 4; i++)
#pragma unroll
        for (int j = 0; j < 4; j++) acc[i][j] = (f32x4){0.f, 0.f, 0.f, 0.f};
    bfrag8 ah0[4], bh0[4], ah1[4], bh1[4], al[4], bl[4];

    auto LDA = [&](const char* base, bfrag8* a) {
#pragma unroll
        for (int i = 0; i < 4; i++)
            a[i] = *(const bfrag8*)(base + (wr * 64 + i * 16 + l15) * 64 + q16);
    };
    auto LDB = [&](const char* base, bfrag8* bv) {
#pragma unroll
        for (int j = 0; j < 4; j++)
            bv[j] = *(const bfrag8*)(base + (wc * 64 + j * 16 + l15) * 64 + q16);
    };
    // MFMA burst; prefetch reads issued inside the setprio region so the
    // scheduler interleaves the independent ds_reads among the MFMAs.
    auto MMAp = [&](const bfrag8* a, const bfrag8* bv, auto pre) {
        __builtin_amdgcn_s_setprio(1);
        pre();
#pragma unroll
        for (int i = 0; i < 4; i++)
#pragma unroll
            for (int j = 0; j < 4; j++)
                acc[i][j] = __builtin_amdgcn_mfma_f32_16x16x32_bf16(a[i], bv[j], acc[i][j], 0, 0, 0);
        __builtin_amdgcn_s_setprio(0);
    };

#define WAITB(N)                                          \
    asm volatile("s_waitcnt vmcnt(" #N ")" ::: "memory"); \
    __builtin_amdgcn_sched_barrier(0);                    \
    __builtin_amdgcn_s_barrier();

    const char* b0 = smem;
    const char* b1 = smem + 32768;

    // prologue (R7 ledger)
    STAGE(Phi, n0, 0, 0);
    STAGE(Phi, m0, 0, 2);
    STAGE(Plo, n0, 0, 1);
    STAGE(Plo, m0, 0, 3);
    STAGE(Phi, n0, 1, 0);
    STAGE(Phi, m0, 1, 2);
    STAGE(Plo, n0, 1, 1);
    WAITB(10)
    // U0U2(0) landed: preload tile-0 hh fragments
    LDA(b0, ah0);
    LDB(b0 + 16384, bh0);

    for (int t = 0; t < 14; t += 2) {
        // ---- even tile t (buf0) ----
        STAGE(Plo, m0, t + 1, 3);
        WAITB(10)  // U1(t)
        MMAp(ah0, bh0, [&] { LDA(b0 + 8192, al); });
        STAGE(Phi, n0, t + 2, 0);
        STAGE(Phi, m0, t + 2, 2);
        WAITB(12)  // U3(t)
        MMAp(al, bh0, [&] { LDB(b0 + 24576, bl); });
        STAGE(Plo, n0, t + 2, 1);
        WAITB(10)  // U0U2(t+1)
        MMAp(ah0, bl, [&] {
            LDA(b1, ah1);
            LDB(b1 + 16384, bh1);
        });
        // ---- odd tile t+1 (buf1) ----
        STAGE(Plo, m0, t + 2, 3);
        WAITB(10)  // U1(t+1)
        MMAp(ah1, bh1, [&] { LDA(b1 + 8192, al); });
        STAGE(Phi, n0, t + 3, 0);
        STAGE(Phi, m0, t + 3, 2);
        WAITB(12)  // U3(t+1)
        MMAp(al, bh1, [&] { LDB(b1 + 24576, bl); });
        STAGE(Plo, n0, t + 3, 1);
        WAITB(10)  // U0U2(t+2)
        MMAp(ah1, bl, [&] {
            LDA(b0, ah0);
            LDB(b0 + 16384, bh0);
        });
    }
    {  // t = 14 (buf0): stage only U3(15); ah0/bh0 preloaded by P3(13)
        STAGE(Plo, m0, 15, 3);
        WAITB(10)  // U1(14)
        MMAp(ah0, bh0, [&] { LDA(b0 + 8192, al); });
        WAITB(8)   // U3(14)
        MMAp(al, bh0, [&] { LDB(b0 + 24576, bl); });
        WAITB(4)   // U0U2(15)
        MMAp(ah0, bl, [&] {
            LDA(b1, ah1);
            LDB(b1 + 16384, bh1);
        });
    }
    {  // t = 15 (buf1): drain
        WAITB(2)   // U1(15)
        MMAp(ah1, bh1, [&] { LDA(b1 + 8192, al); });
        WAITB(0)   // U3(15)
        MMAp(al, bh1, [&] { LDB(b1 + 24576, bl); });
        __builtin_amdgcn_sched_barrier(0);
        __builtin_amdgcn_s_barrier();
        MMAp(ah1, bl, [&] {});
    }
#undef WAITB

    const int col = lane & 15, qr = (lane >> 4) * 4;
#pragma unroll
    for (int i = 0; i < 4; i++)
#pragma unroll
        for (int j = 0; j < 4; j++)
#pragma unroll
            for (int r = 0; r < 4; r++)
                S[(size_t)(n0 + wr * 64 + 16 * i + qr + r) * NSP + m0 + wc * 64 + 16 * j + col] =
                    acc[i][j][r];
    if (!diag) {  // mirror tile via per-wave padded LDS transpose (old-k4 epilogue)
        float* Tbase = (float*)smem;
#pragma unroll
        for (int round = 0; round < 2; round++) {
            __syncthreads();
            if (wr == round) {
                float* T = Tbase + wc * (64 * 68);
#pragma unroll
                for (int i = 0; i < 4; i++)
#pragma unroll
                    for (int j = 0; j < 4; j++)
#pragma unroll
                        for (int r = 0; r < 4; r++)
                            T[(16 * j + col) * 68 + 16 * i + qr + r] = acc[i][j][r];
            }
            __syncthreads();
            if (wr == round) {
                float* T = Tbase + wc * (64 * 68);
                const int rq = (lane & 15) * 4;
#pragma unroll
                for (int rep = 0; rep < 16; rep++) {
                    int cq = rep * 4 + (lane >> 4);
                    float4 v = *(const float4*)(T + cq * 68 + rq);
                    *(float4*)(S + (size_t)(m0 + wc * 64 + cq) * NSP + n0 + wr * 64 + rq) = v;
                }
            }
        }
    }
}

// softmax rows of 4096 over contiguous S0|S1 (grid 8192); writes hi plane only
__global__ __launch_bounds__(256) void k_softmax_pack(float* __restrict__ S) {
    __shared__ float buf[4096];
    __shared__ float red[256];
    const int tid = threadIdx.x;
    float* row = S + (size_t)blockIdx.x * NSP;
    float m = -INFINITY;
#pragma unroll
    for (int it = 0; it < 4; it++) {
        int i = (tid + it * 256) * 4;
        float4 v = *(const float4*)(row + i);
        buf[i] = v.x; buf[i + 1] = v.y; buf[i + 2] = v.z; buf[i + 3] = v.w;
        m = fmaxf(m, fmaxf(fmaxf(v.x, v.y), fmaxf(v.z, v.w)));
    }
    red[tid] = m;
    __syncthreads();
    for (int s = 128; s > 0; s >>= 1) {
        if (tid < s) red[tid] = fmaxf(red[tid], red[tid + s]);
        __syncthreads();
    }
    m = red[0];
    __syncthreads();
    float sum = 0.f;
#pragma unroll
    for (int it = 0; it < 4; it++) {
        int i = (tid + it * 256) * 4;
        float e0 = __expf(buf[i] - m), e1 = __expf(buf[i + 1] - m);
        float e2 = __expf(buf[i + 2] - m), e3 = __expf(buf[i + 3] - m);
        buf[i] = e0; buf[i + 1] = e1; buf[i + 2] = e2; buf[i + 3] = e3;
        sum += e0 + e1 + e2 + e3;
    }
    red[tid] = sum;
    __syncthreads();
    for (int s = 128; s > 0; s >>= 1) {
        if (tid < s) red[tid] += red[tid + s];
        __syncthreads();
    }
    float inv = 1.0f / red[0];
    u16* u = (u16*)row;
#pragma unroll
    for (int it = 0; it < 4; it++) {
        int i = (tid + it * 256) * 4;
        ushort4 hv;
        hv.x = (u16)(__float_as_uint(buf[i] * inv) >> 16);
        hv.y = (u16)(__float_as_uint(buf[i + 1] * inv) >> 16);
        hv.z = (u16)(__float_as_uint(buf[i + 2] * inv) >> 16);
        hv.w = (u16)(__float_as_uint(buf[i + 3] * inv) >> 16);
        *(ushort4*)(u + i) = hv;
    }
}

// ---------------------------------------------------------------------------
// k6 MFMA 1-term, split-K=2, 2 batches/launch — pipelined, single barrier
// per phase (unchanged; passing).
// ---------------------------------------------------------------------------
__global__ __launch_bounds__(512, 2) void k6_mfma(const u16* __restrict__ Yhi0,
                                                  const u16* __restrict__ Ylo0,
                                                  const u16* __restrict__ Su,
                                                  float* __restrict__ Out0,
                                                  float* __restrict__ Pp0,
                                                  float* __restrict__ Pp1) {
    __shared__ __align__(16) char smem[73728];  // 3 x (8KB A + 16KB B)
    const int tid = threadIdx.x, lane = tid & 63, w = tid >> 6;
    const int wr = w >> 2, wc = w & 3;  // 2(c) x 4(m); wave tile 64x64
    const int m0 = blockIdx.x * 256, c0 = blockIdx.y * 128;
    const int rb = blockIdx.z >> 1, kz = blockIdx.z & 1;
    const u16* Yhi = Yhi0 + (size_t)rb * CH * NSP;
    const u16* Ylo = Ylo0 + (size_t)rb * CH * NSP;
    const u16* Pu = Su + (size_t)rb * NSP * NSP * 2;  // S batch stride in u16 units
    float* Out = Out0 + (size_t)rb * CH * NSP;
    float* Ppart = rb ? Pp1 : Pp0;
    const int kb = kz * 2048;
    const int rl = lane >> 2;
    const int cb = (((lane & 3) ^ ((lane >> 3) & 3)) * 8);     // swizzled src chunk
    const int l15 = lane & 15;
    const int q16 = (((lane >> 4) ^ ((lane >> 1) & 3)) * 16);  // swizzled read slot

    // stage K-tile kt into slot: A = Yhi[c0..+128][32], B = Pu[m0..+256][32]
    auto STAGE = [&](int kt, int slot) {
        char* dst = smem + slot * 24576;
        const int k0 = kb + kt * 32;
        gload16(Yhi + (size_t)(c0 + w * 16 + rl) * NSP + k0 + cb, dst + w * 1024);
#pragma unroll
        for (int s = 0; s < 2; s++) {
            int idx = w * 2 + s;
            gload16(Pu + (size_t)(m0 + idx * 16 + rl) * 8192 + k0 + cb,
                    dst + 8192 + idx * 1024);
        }
    };

    f32x4 acc[4][4];
#pragma unroll
    for (int i = 0; i < 4; i++)
#pragma unroll
        for (int j = 0; j < 4; j++) acc[i][j] = (f32x4){0.f, 0.f, 0.f, 0.f};
    bfrag8 ah[4], bh[4];

#define K6PHASE(SLOT, STSLOT, T, DOSTAGE, WN)                                            \
    {                                                                                    \
        const char* bA = smem + (SLOT)*24576;                                            \
        const char* bB = bA + 8192;                                                      \
        _Pragma("unroll") for (int i = 0; i < 4; i++) ah[i] =                            \
            *(const bfrag8*)(bA + (wr * 64 + i * 16 + l15) * 64 + q16);                  \
        _Pragma("unroll") for (int j = 0; j < 4; j++) bh[j] =                            \
            *(const bfrag8*)(bB + (wc * 64 + j * 16 + l15) * 64 + q16);                  \
        if (DOSTAGE) STAGE((T) + 2, (STSLOT));                                           \
        asm volatile("s_waitcnt vmcnt(" #WN ")" ::: "memory");                           \
        __builtin_amdgcn_sched_barrier(0);                                               \
        __builtin_amdgcn_s_barrier();                                                    \
        __builtin_amdgcn_s_setprio(1);                                                   \
        _Pragma("unroll") for (int i = 0; i < 4; i++)                                    \
            _Pragma("unroll") for (int j = 0; j < 4; j++) acc[i][j] =                    \
                __builtin_amdgcn_mfma_f32_16x16x32_bf16(ah[i], bh[j], acc[i][j], 0, 0, 0); \
        __builtin_amdgcn_s_setprio(0);                                                   \
    }

    // prologue: tiles 0,1 in flight; wait tile 0
    STAGE(0, 0);
    STAGE(1, 1);
    asm volatile("s_waitcnt vmcnt(3)" ::: "memory");
    __builtin_amdgcn_sched_barrier(0);
    __builtin_amdgcn_s_barrier();

    for (int tt = 0; tt < 60; tt += 3) {
        K6PHASE(0, 2, tt, true, 3)
        K6PHASE(1, 0, tt + 1, true, 3)
        K6PHASE(2, 1, tt + 2, true, 3)
    }
    K6PHASE(0, 2, 60, true, 3)   // stages 62 -> slot 2
    K6PHASE(1, 0, 61, true, 3)   // stages 63 -> slot 0
    K6PHASE(2, 0, 62, false, 0)  // drain: tile 63 landed
    K6PHASE(0, 0, 63, false, 0)
#undef K6PHASE

    const int col = lane & 15, qr = (lane >> 4) * 4;
    if (kz == 0) {
#pragma unroll
        for (int i = 0; i < 4; i++)
#pragma unroll
            for (int j = 0; j < 4; j++)
#pragma unroll
                for (int r = 0; r < 4; r++) {
                    int c = c0 + wr * 64 + 16 * i + qr + r;
                    int mm = m0 + wc * 64 + 16 * j + col;
                    Out[(size_t)c * NSP + mm] =
                        acc[i][j][r] +
                        join_bf16(Yhi[(size_t)c * NSP + mm], Ylo[(size_t)c * NSP + mm]);
                }
    } else {
#pragma unroll
        for (int i = 0; i < 4; i++)
#pragma unroll
            for (int j = 0; j < 4; j++)
#pragma unroll
                for (int r = 0; r < 4; r++) {
                    int c = c0 + wr * 64 + 16 * i + qr + r;
                    int mm = m0 + wc * 64 + 16 * j + col;
                    Ppart[(size_t)c * NSP + mm] = acc[i][j][r];
                }
    }
}

// out[b] += Ppart[b] for the round's 2 batches
__global__ __launch_bounds__(256) void k_fixup(float* __restrict__ Out0,
                                               const float* __restrict__ Pp0,
                                               const float* __restrict__ Pp1) {
    const size_t CN = (size_t)CH * NSP;
    const int b = blockIdx.y;
    const float* P = b ? Pp1 : Pp0;
    float* O = Out0 + (size_t)b * CN;
    size_t i = ((size_t)blockIdx.x * 256 + threadIdx.x) * 4;
    float4 o = *(const float4*)(O + i);
    float4 a = *(const float4*)(P + i);
    o.x += a.x; o.y += a.y; o.z += a.z; o.w += a.w;
    *(float4*)(O + i) = o;
}

extern "C" void kernel_launch(void* const* d_in, const int* in_sizes, int n_in,
                              void* d_out, int out_size, void* d_ws, size_t ws_size,
                              hipStream_t stream) {
    const float* x = (const float*)d_in[0];
    float* out = (float*)d_out;

    // workspace layout (196 MB):
    //   [0,128MB): S0|S1 fp32 score buffers; aliased by X-prep [0,96MB) (dead after k3)
    //   [128,192MB): Yhi|Ylo|YThi|YTlo (YT per-batch 4MB slices)
    //       Pk (k1 partials, 32MB) aliases Yhi|Ylo (dead before k3)
    //       k6 round-r partials alias the YT slices of round r's batches (dead after k4)
    //   [192,196MB): Lg
    char* p = (char*)d_ws;
    const size_t SZ16 = (size_t)BATCH * CH * NSP * 2;  // 16 MB
    const size_t HALF = SZ16 / 2;                      // 8 MB = CH*NSP*4
    u16* XHi = (u16*)p;
    u16* XLo = (u16*)(p + SZ16);
    u16* XT2hi = (u16*)(p + 2 * SZ16);
    u16* XT2lo = (u16*)(p + 3 * SZ16);
    u16* XT1hi = (u16*)(p + 4 * SZ16);
    u16* XT1lo = (u16*)(p + 5 * SZ16);
    float* S = (float*)p;
    u16* Yhi = (u16*)(p + 8 * SZ16);
    u16* Ylo = (u16*)(p + 9 * SZ16);
    u16* YThi = (u16*)(p + 10 * SZ16);
    u16* YTlo = (u16*)(p + 11 * SZ16);
    float* Pk = (float*)(p + 8 * SZ16);
    float* Lg = (float*)(p + 12 * SZ16);

    // Stage 1: channel attention
    k_prep_cn<<<dim3(NSP / 64, CH / 64, BATCH), 256, 0, stream>>>(x, XHi, XLo, XT1hi, XT1lo);
    k_prep_nc<<<dim3(NSP / 64, CH / 64, BATCH), 256, 0, stream>>>(x, XT2hi, XT2lo);
    k1_mfma<<<dim3(512), 256, 0, stream>>>(XHi, XLo, XT2hi, XT2lo, Pk);
    k_combine8<<<dim3((BATCH * CH * CH) / (4 * 256)), 256, 0, stream>>>(Pk, Lg);
    k_softmax_pack512<<<dim3(BATCH * CH), 256, 0, stream>>>(Lg);
    k3_mfma<<<dim3(NSP / 128, CH / 128, BATCH), 256, 0, stream>>>((const u16*)Lg, XT1hi, XT1lo, x,
                                                                  Yhi, Ylo, YThi, YTlo);

    // Stage 2: positional attention, 2 batches per round
    const int TRI = (NSP / 128) * (NSP / 128 + 1) / 2;  // 528
    for (int round = 0; round < 2; round++) {
        const size_t b0 = (size_t)(2 * round);
        float* Pp0 = (float*)((char*)YThi + round * HALF);
        float* Pp1 = (float*)((char*)YTlo + round * HALF);
        k4_mfma<<<dim3(TRI, 2), 256, 0, stream>>>(YThi + b0 * NSP * CH, YTlo + b0 * NSP * CH, S);
        k_softmax_pack<<<dim3(2 * NSP), 256, 0, stream>>>(S);
        k6_mfma<<<dim3(NSP / 256, CH / 128, 4), 512, 0, stream>>>(Yhi + b0 * CH * NSP,
                                                                  Ylo + b0 * CH * NSP,
                                                                  (const u16*)S,
                                                                  out + b0 * CH * NSP, Pp0, Pp1);
        k_fixup<<<dim3((CH * NSP) / (4 * 256), 2), 256, 0, stream>>>(out + b0 * CH * NSP, Pp0, Pp1);
    }
}